// Round 1
// baseline (2485.150 us; speedup 1.0000x reference)
//
#include <hip/hip_runtime.h>
#include <math.h>

#define SEQ 2048
#define HID_DIM 2048
#define NH 16
#define NKV 4
#define HD 128

typedef float  f4v  __attribute__((ext_vector_type(4)));
typedef __bf16 bf8v __attribute__((ext_vector_type(8)));
typedef __bf16 bf4v __attribute__((ext_vector_type(4)));

// C[M,N] = sum_src A_s[M,K] (row-major) * B_s[N,K]^T (row-major, i.e. NT GEMM)
// bf16 MFMA 16x16x32, fp32 accumulate. 64x64 tile, BK=32, 256 threads (4 waves).
__global__ __launch_bounds__(256)
void gemm_bt(const float* __restrict__ A0, const float* __restrict__ A1,
             const float* __restrict__ B0, const float* __restrict__ B1,
             float* __restrict__ C, int M, int N, int K)
{
    __shared__ __bf16 As[64 * 32];
    __shared__ __bf16 Bs[64 * 32];
    const int tid  = threadIdx.x;
    const int lane = tid & 63, w = tid >> 6;
    const int m0 = blockIdx.y * 64, n0 = blockIdx.x * 64;
    const int mm = lane & 15, quad = lane >> 4;

    f4v acc[4];
#pragma unroll
    for (int c = 0; c < 4; ++c) acc[c] = f4v{0.f, 0.f, 0.f, 0.f};

    for (int src = 0; src < 2; ++src) {
        const float* Ap = src ? A1 : A0;
        const float* Bp = src ? B1 : B0;
        if (Ap == nullptr) break;
        for (int k0 = 0; k0 < K; k0 += 32) {
            // stage 64x32 fp32 tiles of A and B, converting to bf16
#pragma unroll
            for (int half = 0; half < 2; ++half) {
                int f   = tid + half * 256;      // float4 index, 512 total
                int row = f >> 3, c4 = (f & 7) * 4;
                float4 va = *reinterpret_cast<const float4*>(&Ap[(size_t)(m0 + row) * K + k0 + c4]);
                float4 vb = *reinterpret_cast<const float4*>(&Bp[(size_t)(n0 + row) * K + k0 + c4]);
                bf4v pa = { (__bf16)va.x, (__bf16)va.y, (__bf16)va.z, (__bf16)va.w };
                bf4v pb = { (__bf16)vb.x, (__bf16)vb.y, (__bf16)vb.z, (__bf16)vb.w };
                *reinterpret_cast<bf4v*>(&As[row * 32 + c4]) = pa;
                *reinterpret_cast<bf4v*>(&Bs[row * 32 + c4]) = pb;
            }
            __syncthreads();
            // A fragment: rows w*16 + (lane&15), k = quad*8 + j
            bf8v a = *reinterpret_cast<const bf8v*>(&As[(w * 16 + mm) * 32 + quad * 8]);
#pragma unroll
            for (int c = 0; c < 4; ++c) {
                bf8v b = *reinterpret_cast<const bf8v*>(&Bs[(c * 16 + mm) * 32 + quad * 8]);
                acc[c] = __builtin_amdgcn_mfma_f32_16x16x32_bf16(a, b, acc[c], 0, 0, 0);
            }
            __syncthreads();
        }
    }
    // D layout: col = lane&15, row = quad*4 + r
#pragma unroll
    for (int c = 0; c < 4; ++c)
#pragma unroll
        for (int r = 0; r < 4; ++r)
            C[(size_t)(m0 + w * 16 + quad * 4 + r) * N + n0 + c * 16 + mm] = acc[c][r];
}

// Per-(token, head) RMSNorm + RoPE. blockIdx.y < NH -> q head (also applies
// 1/sqrt(HD) softmax scale), else k head. 64 threads: lane l owns dims l, l+64.
__global__ __launch_bounds__(64)
void norm_rope(float* __restrict__ q, float* __restrict__ k,
               const float* __restrict__ qw, const float* __restrict__ kw)
{
    const int s = blockIdx.x, hh = blockIdx.y, l = threadIdx.x;
    float* p; const float* wn; float scale;
    if (hh < NH) { p = q + (size_t)s * (NH * HD) + hh * HD;        wn = qw; scale = 0.08838834764831845f; }
    else         { p = k + (size_t)s * (NKV * HD) + (hh - NH) * HD; wn = kw; scale = 1.0f; }
    float x0 = p[l], x1 = p[l + 64];
    float ss = x0 * x0 + x1 * x1;
#pragma unroll
    for (int off = 32; off; off >>= 1) ss += __shfl_xor(ss, off);
    float inv = rsqrtf(ss * (1.0f / 128.0f) + 1e-6f);
    x0 *= inv * wn[l];
    x1 *= inv * wn[l + 64];
    // inv_freq = 10000^(-l/64) ; cos/sin identical for dims l and l+64
    float invf = exp2f(-(float)l * (13.287712379549449f / 64.0f));
    float ang  = (float)s * invf;
    float c, sn;
    sincosf(ang, &sn, &c);
    p[l]      = (x0 * c - x1 * sn) * scale;
    p[l + 64] = (x1 * c + x0 * sn) * scale;
}

// Causal GQA flash attention, fp32. Block = 4 waves = 4 query rows of one head.
// K/V staged in LDS 64-key chunks (row stride 129 -> conflict-free).
__global__ __launch_bounds__(256)
void attn(const float* __restrict__ q, const float* __restrict__ k,
          const float* __restrict__ v, float* __restrict__ o)
{
    __shared__ float kbuf[64 * 129];
    __shared__ float vbuf[64 * 129];
    __shared__ float qs[4 * 128];
    const int tid = threadIdx.x, lane = tid & 63, w = tid >> 6;
    const int h = blockIdx.y, kh = h >> 2;
    const int i0 = blockIdx.x * 4, i = i0 + w;

    const float* qrow = q + (size_t)i * (NH * HD) + h * HD;
    qs[w * 128 + lane]      = qrow[lane];
    qs[w * 128 + 64 + lane] = qrow[64 + lane];

    float m = -__builtin_inff(), l = 0.f, acc0 = 0.f, acc1 = 0.f;
    const int nch = i0 / 64 + 1;   // all 4 rows of the block share chunk count
    for (int c = 0; c < nch; ++c) {
#pragma unroll
        for (int t = 0; t < 8; ++t) {
            int f = tid + t * 256;           // float4 idx in [0, 2048)
            int row = f >> 5, c4 = (f & 31) * 4;
            size_t g = (size_t)(c * 64 + row) * (NKV * HD) + kh * HD + c4;
            float4 kv4 = *reinterpret_cast<const float4*>(&k[g]);
            float4 vv4 = *reinterpret_cast<const float4*>(&v[g]);
            int lidx = row * 129 + c4;
            kbuf[lidx + 0] = kv4.x; kbuf[lidx + 1] = kv4.y; kbuf[lidx + 2] = kv4.z; kbuf[lidx + 3] = kv4.w;
            vbuf[lidx + 0] = vv4.x; vbuf[lidx + 1] = vv4.y; vbuf[lidx + 2] = vv4.z; vbuf[lidx + 3] = vv4.w;
        }
        __syncthreads();
        // lane j: score for key c*64+j (q pre-scaled by 1/sqrt(HD))
        float sacc = 0.f;
#pragma unroll 8
        for (int d = 0; d < 128; ++d)
            sacc += qs[w * 128 + d] * kbuf[lane * 129 + d];
        int jj = c * 64 + lane;
        if (jj > i) sacc = -__builtin_inff();
        float cmax = sacc;
#pragma unroll
        for (int off = 32; off; off >>= 1) cmax = fmaxf(cmax, __shfl_xor(cmax, off));
        float mnew  = fmaxf(m, cmax);
        float alpha = __expf(m - mnew);      // exp(-inf) = 0 on first chunk
        float pp    = __expf(sacc - mnew);
        float psum  = pp;
#pragma unroll
        for (int off = 32; off; off >>= 1) psum += __shfl_xor(psum, off);
        l = l * alpha + psum;
        acc0 *= alpha; acc1 *= alpha;
        m = mnew;
#pragma unroll 8
        for (int j = 0; j < 64; ++j) {
            float pj = __shfl(pp, j);
            acc0 += pj * vbuf[j * 129 + lane];
            acc1 += pj * vbuf[j * 129 + 64 + lane];
        }
        __syncthreads();
    }
    float invl = 1.f / l;
    o[(size_t)i * (NH * HD) + h * HD + lane]      = acc0 * invl;
    o[(size_t)i * (NH * HD) + h * HD + 64 + lane] = acc1 * invl;
}

extern "C" void kernel_launch(void* const* d_in, const int* in_sizes, int n_in,
                              void* d_out, int out_size, void* d_ws, size_t ws_size,
                              hipStream_t stream)
{
    const float* hs  = (const float*)d_in[0];
    const float* mu  = (const float*)d_in[1];
    const float* wq  = (const float*)d_in[2];
    const float* wk  = (const float*)d_in[3];
    const float* wv  = (const float*)d_in[4];
    const float* wo  = (const float*)d_in[5];
    const float* wmq = (const float*)d_in[6];
    const float* wmk = (const float*)d_in[7];
    const float* wmv = (const float*)d_in[8];
    const float* qw  = (const float*)d_in[9];
    const float* kw  = (const float*)d_in[10];
    float* out = (float*)d_out;

    float* ws = (float*)d_ws;
    float* qb = ws;                         // [2048, 2048]  16 MB
    float* kb = ws + (size_t)4 * 1024 * 1024; // [2048, 512]   4 MB
    float* vb = ws + (size_t)5 * 1024 * 1024; // [2048, 512]   4 MB
    float* ab = ws + (size_t)6 * 1024 * 1024; // [2048, 2048] 16 MB

    dim3 blk(256);
    gemm_bt<<<dim3(HID_DIM / 64, SEQ / 64), blk, 0, stream>>>(hs, mu, wq, wmq, qb, SEQ, NH * HD, HID_DIM);
    gemm_bt<<<dim3((NKV * HD) / 64, SEQ / 64), blk, 0, stream>>>(hs, mu, wk, wmk, kb, SEQ, NKV * HD, HID_DIM);
    gemm_bt<<<dim3((NKV * HD) / 64, SEQ / 64), blk, 0, stream>>>(hs, mu, wv, wmv, vb, SEQ, NKV * HD, HID_DIM);
    norm_rope<<<dim3(SEQ, NH + NKV), dim3(64), 0, stream>>>(qb, kb, qw, kw);
    attn<<<dim3(SEQ / 4, NH), blk, 0, stream>>>(qb, kb, vb, ab);
    gemm_bt<<<dim3(HID_DIM / 64, SEQ / 64), blk, 0, stream>>>(ab, nullptr, wo, nullptr, out, SEQ, HID_DIM, NH * HD);
}

// Round 2
// 937.167 us; speedup vs baseline: 2.6518x; 2.6518x over previous
//
#include <hip/hip_runtime.h>
#include <math.h>

#define SEQ 2048
#define HID_DIM 2048
#define NH 16
#define NKV 4
#define HD 128

typedef float  f4v  __attribute__((ext_vector_type(4)));
typedef __bf16 bf8v __attribute__((ext_vector_type(8)));
typedef __bf16 bf4v __attribute__((ext_vector_type(4)));
typedef __bf16 bf2v __attribute__((ext_vector_type(2)));

// C[M,N] = sum_src A_s[M,K] (row-major) * B_s[N,K]^T (NT GEMM)
// bf16 MFMA 16x16x32, fp32 accumulate. 64x64 tile, BK=32, 256 threads.
__global__ __launch_bounds__(256)
void gemm_bt(const float* __restrict__ A0, const float* __restrict__ A1,
             const float* __restrict__ B0, const float* __restrict__ B1,
             float* __restrict__ C, int M, int N, int K)
{
    __shared__ __bf16 As[64 * 32];
    __shared__ __bf16 Bs[64 * 32];
    const int tid  = threadIdx.x;
    const int lane = tid & 63, w = tid >> 6;
    const int m0 = blockIdx.y * 64, n0 = blockIdx.x * 64;
    const int mm = lane & 15, quad = lane >> 4;

    f4v acc[4];
#pragma unroll
    for (int c = 0; c < 4; ++c) acc[c] = f4v{0.f, 0.f, 0.f, 0.f};

    for (int src = 0; src < 2; ++src) {
        const float* Ap = src ? A1 : A0;
        const float* Bp = src ? B1 : B0;
        if (Ap == nullptr) break;
        for (int k0 = 0; k0 < K; k0 += 32) {
#pragma unroll
            for (int half = 0; half < 2; ++half) {
                int f   = tid + half * 256;
                int row = f >> 3, c4 = (f & 7) * 4;
                float4 va = *reinterpret_cast<const float4*>(&Ap[(size_t)(m0 + row) * K + k0 + c4]);
                float4 vb = *reinterpret_cast<const float4*>(&Bp[(size_t)(n0 + row) * K + k0 + c4]);
                bf4v pa = { (__bf16)va.x, (__bf16)va.y, (__bf16)va.z, (__bf16)va.w };
                bf4v pb = { (__bf16)vb.x, (__bf16)vb.y, (__bf16)vb.z, (__bf16)vb.w };
                *reinterpret_cast<bf4v*>(&As[row * 32 + c4]) = pa;
                *reinterpret_cast<bf4v*>(&Bs[row * 32 + c4]) = pb;
            }
            __syncthreads();
            bf8v a = *reinterpret_cast<const bf8v*>(&As[(w * 16 + mm) * 32 + quad * 8]);
#pragma unroll
            for (int c = 0; c < 4; ++c) {
                bf8v b = *reinterpret_cast<const bf8v*>(&Bs[(c * 16 + mm) * 32 + quad * 8]);
                acc[c] = __builtin_amdgcn_mfma_f32_16x16x32_bf16(a, b, acc[c], 0, 0, 0);
            }
            __syncthreads();
        }
    }
#pragma unroll
    for (int c = 0; c < 4; ++c)
#pragma unroll
        for (int r = 0; r < 4; ++r)
            C[(size_t)(m0 + w * 16 + quad * 4 + r) * N + n0 + c * 16 + mm] = acc[c][r];
}

// Per-(token, head) RMSNorm + RoPE (q also gets 1/sqrt(HD) softmax scale).
__global__ __launch_bounds__(64)
void norm_rope(float* __restrict__ q, float* __restrict__ k,
               const float* __restrict__ qw, const float* __restrict__ kw)
{
    const int s = blockIdx.x, hh = blockIdx.y, l = threadIdx.x;
    float* p; const float* wn; float scale;
    if (hh < NH) { p = q + (size_t)s * (NH * HD) + hh * HD;        wn = qw; scale = 0.08838834764831845f; }
    else         { p = k + (size_t)s * (NKV * HD) + (hh - NH) * HD; wn = kw; scale = 1.0f; }
    float x0 = p[l], x1 = p[l + 64];
    float ss = x0 * x0 + x1 * x1;
#pragma unroll
    for (int off = 32; off; off >>= 1) ss += __shfl_xor(ss, off);
    float inv = rsqrtf(ss * (1.0f / 128.0f) + 1e-6f);
    x0 *= inv * wn[l];
    x1 *= inv * wn[l + 64];
    float invf = exp2f(-(float)l * (13.287712379549449f / 64.0f));
    float ang  = (float)s * invf;
    float c, sn;
    sincosf(ang, &sn, &c);
    p[l]      = (x0 * c - x1 * sn) * scale;
    p[l + 64] = (x1 * c + x0 * sn) * scale;
}

// MFMA flash attention, causal GQA. Block = 256 thr = 4 waves; each wave owns
// 16 query rows of a 64-row q-tile. K-tiles of 64 keys staged in LDS (bf16).
// V staged transposed [dim][key] with xor-swizzled key-pair columns:
// coalesced global reads + ~4-way LDS scatter writes + clean b128 frag reads.
// Q-tiles paired (p, 31-p) per block -> uniform 33 key-tiles/block.
__global__ __launch_bounds__(256)
void attn_mfma(const float* __restrict__ q, const float* __restrict__ k,
               const float* __restrict__ v, float* __restrict__ o)
{
    __shared__ __bf16 Ks[64 * 136];      // [key][dim], stride 136
    __shared__ __bf16 Vt[128 * 72];      // [dim][key], stride 72, swizzled pairs
    __shared__ __bf16 Ps[4][16 * 72];    // per-wave P strip [q][key]

    const int tid = threadIdx.x, lane = tid & 63, w = tid >> 6;
    const int mm = lane & 15, quad = lane >> 4;
    const int h = blockIdx.y, kh = h >> 2;
    const int pp = blockIdx.x;

    for (int half = 0; half < 2; ++half) {
        const int qt = half ? (31 - pp) : pp;

        // Q fragments direct from global (A-layout: m=mm row, k=ks*32+quad*8+j)
        bf8v aq[4];
        const float* qbase = q + (size_t)(qt * 64 + w * 16 + mm) * (NH * HD) + h * HD;
#pragma unroll
        for (int ks = 0; ks < 4; ++ks) {
            float4 f0 = *reinterpret_cast<const float4*>(qbase + ks * 32 + quad * 8);
            float4 f1 = *reinterpret_cast<const float4*>(qbase + ks * 32 + quad * 8 + 4);
            aq[ks] = bf8v{ (__bf16)f0.x, (__bf16)f0.y, (__bf16)f0.z, (__bf16)f0.w,
                           (__bf16)f1.x, (__bf16)f1.y, (__bf16)f1.z, (__bf16)f1.w };
        }

        float mrow[4], lrow[4];
        f4v oacc[8];
#pragma unroll
        for (int r = 0; r < 4; ++r) { mrow[r] = -__builtin_inff(); lrow[r] = 0.f; }
#pragma unroll
        for (int nb = 0; nb < 8; ++nb) oacc[nb] = f4v{0.f, 0.f, 0.f, 0.f};

        for (int kt = 0; kt <= qt; ++kt) {
            __syncthreads();   // protect previous tile's Ks/Vt
            // ---- stage K tile: [64 keys][128 dims] -> bf16, coalesced ----
#pragma unroll
            for (int t = 0; t < 8; ++t) {
                int f = tid + t * 256;           // 2048 float4s
                int row = f >> 5, c4 = (f & 31) * 4;
                float4 kv = *reinterpret_cast<const float4*>(
                    &k[(size_t)(kt * 64 + row) * (NKV * HD) + kh * HD + c4]);
                *reinterpret_cast<bf4v*>(&Ks[row * 136 + c4]) =
                    bf4v{ (__bf16)kv.x, (__bf16)kv.y, (__bf16)kv.z, (__bf16)kv.w };
            }
            // ---- stage V transposed, swizzled pair columns ----
#pragma unroll
            for (int t = 0; t < 4; ++t) {
                int f  = tid + t * 256;          // 1024 = 32 pairs x 32 dim-groups
                int kp = f >> 5;                 // key pair: keys 2kp, 2kp+1
                int c4 = (f & 31) * 4;           // dims c4..c4+3
                const float* vr = &v[(size_t)(kt * 64 + 2 * kp) * (NKV * HD) + kh * HD + c4];
                float4 v0 = *reinterpret_cast<const float4*>(vr);
                float4 v1 = *reinterpret_cast<const float4*>(vr + NKV * HD);
#pragma unroll
                for (int i = 0; i < 4; ++i) {
                    int d   = c4 + i;
                    int col = kp ^ (((d >> 2) & 7) << 2);
                    float e0 = (i == 0) ? v0.x : (i == 1) ? v0.y : (i == 2) ? v0.z : v0.w;
                    float e1 = (i == 0) ? v1.x : (i == 1) ? v1.y : (i == 2) ? v1.z : v1.w;
                    *reinterpret_cast<bf2v*>(
                        reinterpret_cast<char*>(Vt) + d * 144 + col * 4) =
                        bf2v{ (__bf16)e0, (__bf16)e1 };
                }
            }
            __syncthreads();

            // ---- S = Q K^T (16x64 per wave) ----
            f4v s[4];
#pragma unroll
            for (int c = 0; c < 4; ++c) s[c] = f4v{0.f, 0.f, 0.f, 0.f};
#pragma unroll
            for (int ks = 0; ks < 4; ++ks) {
#pragma unroll
                for (int c = 0; c < 4; ++c) {
                    bf8v b = *reinterpret_cast<const bf8v*>(&Ks[(c * 16 + mm) * 136 + ks * 32 + quad * 8]);
                    s[c] = __builtin_amdgcn_mfma_f32_16x16x32_bf16(aq[ks], b, s[c], 0, 0, 0);
                }
            }
            // ---- causal mask on diagonal tile ----
            if (kt == qt) {
#pragma unroll
                for (int c = 0; c < 4; ++c)
#pragma unroll
                    for (int r = 0; r < 4; ++r)
                        if (c * 16 + mm > w * 16 + quad * 4 + r)
                            s[c][r] = -__builtin_inff();
            }
            // ---- online softmax (rows owned by quad-group, 16 lanes/cols) ----
            float pr[4][4];
#pragma unroll
            for (int r = 0; r < 4; ++r) {
                float cm = fmaxf(fmaxf(s[0][r], s[1][r]), fmaxf(s[2][r], s[3][r]));
#pragma unroll
                for (int off = 8; off; off >>= 1) cm = fmaxf(cm, __shfl_xor(cm, off));
                float mnew  = fmaxf(mrow[r], cm);
                float alpha = __expf(mrow[r] - mnew);
                mrow[r] = mnew;
                float rs = 0.f;
#pragma unroll
                for (int c = 0; c < 4; ++c) { pr[c][r] = __expf(s[c][r] - mnew); rs += pr[c][r]; }
#pragma unroll
                for (int off = 8; off; off >>= 1) rs += __shfl_xor(rs, off);
                lrow[r] = lrow[r] * alpha + rs;
#pragma unroll
                for (int nb = 0; nb < 8; ++nb) oacc[nb][r] *= alpha;
            }
            // ---- write P strip (C-layout -> A-layout via LDS, pair-packed) ----
#pragma unroll
            for (int c = 0; c < 4; ++c)
#pragma unroll
                for (int r = 0; r < 4; ++r) {
                    float mine  = pr[c][r];
                    float other = __shfl_xor(mine, 1);
                    if ((mm & 1) == 0) {
                        *reinterpret_cast<bf2v*>(
                            reinterpret_cast<char*>(&Ps[w][0]) + (quad * 4 + r) * 144 + (c * 16 + mm) * 2) =
                            bf2v{ (__bf16)mine, (__bf16)other };
                    }
                }
            // ---- O += P V  (wave-private P strip, no barrier needed) ----
            bf8v pa[2];
#pragma unroll
            for (int kb = 0; kb < 2; ++kb)
                pa[kb] = *reinterpret_cast<const bf8v*>(
                    reinterpret_cast<const char*>(&Ps[w][0]) + mm * 144 + kb * 64 + quad * 16);
#pragma unroll
            for (int nb = 0; nb < 8; ++nb) {
                int d  = nb * 16 + mm;
                int xr = ((d >> 2) & 7) << 2;
#pragma unroll
                for (int kb = 0; kb < 2; ++kb) {
                    int gp = (kb * 16 + quad * 4) ^ xr;
                    bf8v bv = *reinterpret_cast<const bf8v*>(
                        reinterpret_cast<const char*>(Vt) + d * 144 + gp * 4);
                    oacc[nb] = __builtin_amdgcn_mfma_f32_16x16x32_bf16(pa[kb], bv, oacc[nb], 0, 0, 0);
                }
            }
        }
        // ---- epilogue ----
#pragma unroll
        for (int r = 0; r < 4; ++r) {
            float invl = 1.f / lrow[r];
            size_t row = (size_t)(qt * 64 + w * 16 + quad * 4 + r) * (NH * HD) + h * HD;
#pragma unroll
            for (int nb = 0; nb < 8; ++nb)
                o[row + nb * 16 + mm] = oacc[nb][r] * invl;
        }
    }
}

extern "C" void kernel_launch(void* const* d_in, const int* in_sizes, int n_in,
                              void* d_out, int out_size, void* d_ws, size_t ws_size,
                              hipStream_t stream)
{
    const float* hs  = (const float*)d_in[0];
    const float* mu  = (const float*)d_in[1];
    const float* wq  = (const float*)d_in[2];
    const float* wk  = (const float*)d_in[3];
    const float* wv  = (const float*)d_in[4];
    const float* wo  = (const float*)d_in[5];
    const float* wmq = (const float*)d_in[6];
    const float* wmk = (const float*)d_in[7];
    const float* wmv = (const float*)d_in[8];
    const float* qw  = (const float*)d_in[9];
    const float* kw  = (const float*)d_in[10];
    float* out = (float*)d_out;

    float* ws = (float*)d_ws;
    float* qb = ws;                           // [2048, 2048]  16 MB
    float* kb = ws + (size_t)4 * 1024 * 1024; // [2048, 512]    4 MB
    float* vb = ws + (size_t)5 * 1024 * 1024; // [2048, 512]    4 MB
    float* ab = ws + (size_t)6 * 1024 * 1024; // [2048, 2048]  16 MB

    dim3 blk(256);
    gemm_bt<<<dim3(HID_DIM / 64, SEQ / 64), blk, 0, stream>>>(hs, mu, wq, wmq, qb, SEQ, NH * HD, HID_DIM);
    gemm_bt<<<dim3((NKV * HD) / 64, SEQ / 64), blk, 0, stream>>>(hs, mu, wk, wmk, kb, SEQ, NKV * HD, HID_DIM);
    gemm_bt<<<dim3((NKV * HD) / 64, SEQ / 64), blk, 0, stream>>>(hs, mu, wv, wmv, vb, SEQ, NKV * HD, HID_DIM);
    norm_rope<<<dim3(SEQ, NH + NKV), dim3(64), 0, stream>>>(qb, kb, qw, kw);
    attn_mfma<<<dim3(16, NH), blk, 0, stream>>>(qb, kb, vb, ab);
    gemm_bt<<<dim3(HID_DIM / 64, SEQ / 64), blk, 0, stream>>>(ab, nullptr, wo, nullptr, out, SEQ, HID_DIM, NH * HD);
}

// Round 3
// 527.461 us; speedup vs baseline: 4.7115x; 1.7768x over previous
//
#include <hip/hip_runtime.h>
#include <math.h>

#define SEQ 2048
#define HID_DIM 2048
#define NH 16
#define NKV 4
#define HD 128
#define QS 3072   // fused qkv row stride (floats): [q 2048 | k 512 | v 512]

typedef float  f4v  __attribute__((ext_vector_type(4)));
typedef __bf16 bf8v __attribute__((ext_vector_type(8)));
typedef __bf16 bf4v __attribute__((ext_vector_type(4)));
typedef __bf16 bf2v __attribute__((ext_vector_type(2)));

typedef __attribute__((address_space(1))) const void* gvp;
typedef __attribute__((address_space(3))) void*       svp;

__device__ __forceinline__ void gld16(const void* g, void* lds_wave_base) {
    __builtin_amdgcn_global_load_lds((gvp)g, (svp)lds_wave_base, 16, 0, 0);
}

// ---- fp32 -> bf16 converts ---------------------------------------------
// dst[row][0:K) = s0 row, dst[row][K:2K) = s1 row   (kq = K/4)
__global__ __launch_bounds__(256)
void cvt_cat2(__bf16* __restrict__ dst, const float* __restrict__ s0,
              const float* __restrict__ s1, int rows, int kq)
{
    int i = blockIdx.x * 256 + threadIdx.x;
    if (i >= rows * kq * 2) return;
    int row = i / (2 * kq), c = i - row * 2 * kq;
    const float* s = (c < kq) ? s0 + ((size_t)row * kq + c) * 4
                              : s1 + ((size_t)row * kq + (c - kq)) * 4;
    float4 v = *reinterpret_cast<const float4*>(s);
    *reinterpret_cast<bf4v*>(dst + ((size_t)row * 2 * kq + c) * 4) =
        bf4v{ (__bf16)v.x, (__bf16)v.y, (__bf16)v.z, (__bf16)v.w };
}

__global__ __launch_bounds__(256)
void cvt(__bf16* __restrict__ dst, const float* __restrict__ src, int n4)
{
    int i = blockIdx.x * 256 + threadIdx.x;
    if (i >= n4) return;
    float4 v = *reinterpret_cast<const float4*>(src + (size_t)i * 4);
    *reinterpret_cast<bf4v*>(dst + (size_t)i * 4) =
        bf4v{ (__bf16)v.x, (__bf16)v.y, (__bf16)v.z, (__bf16)v.w };
}

// ---- m97-style NT GEMM: C[M,N] f32 = A[M,K] bf16 . B[N,K]^T bf16 -------
// 128x128 tile, BK=32, 256 thr (2x2 waves of 64x64). global_load_lds x16.
__global__ __launch_bounds__(256)
void gemm_nt(const __bf16* __restrict__ A, const __bf16* __restrict__ B,
             float* __restrict__ C, int M, int N, int K)
{
    __shared__ __bf16 As[128 * 32];
    __shared__ __bf16 Bs[128 * 32];
    const int tid = threadIdx.x, lane = tid & 63, w = tid >> 6;
    const int wm = w >> 1, wn = w & 1;
    const int mm = lane & 15, quad = lane >> 4;
    const int m0 = blockIdx.y * 128, n0 = blockIdx.x * 128;
    const int r0 = lane >> 2, c0 = (lane & 3) * 8;   // staging row/col per lane

    f4v acc[4][4] = {};

    for (int k0 = 0; k0 < K; k0 += 32) {
#pragma unroll
        for (int j = 0; j < 2; ++j) {
            int chunk = w * 2 + j;                   // 0..7 -> 1 KiB LDS each
            int row   = chunk * 16 + r0;
            gld16(&A[(size_t)(m0 + row) * K + k0 + c0], (char*)As + chunk * 1024);
            gld16(&B[(size_t)(n0 + row) * K + k0 + c0], (char*)Bs + chunk * 1024);
        }
        __syncthreads();
        bf8v af[4], bf[4];
#pragma unroll
        for (int t = 0; t < 4; ++t) {
            af[t] = *reinterpret_cast<const bf8v*>(&As[(wm * 64 + t * 16 + mm) * 32 + quad * 8]);
            bf[t] = *reinterpret_cast<const bf8v*>(&Bs[(wn * 64 + t * 16 + mm) * 32 + quad * 8]);
        }
#pragma unroll
        for (int mt = 0; mt < 4; ++mt)
#pragma unroll
            for (int nt = 0; nt < 4; ++nt)
                acc[mt][nt] = __builtin_amdgcn_mfma_f32_16x16x32_bf16(af[mt], bf[nt], acc[mt][nt], 0, 0, 0);
        __syncthreads();
    }
#pragma unroll
    for (int mt = 0; mt < 4; ++mt)
#pragma unroll
        for (int nt = 0; nt < 4; ++nt)
#pragma unroll
            for (int r = 0; r < 4; ++r)
                C[(size_t)(m0 + wm * 64 + mt * 16 + quad * 4 + r) * N
                  + n0 + wn * 64 + nt * 16 + mm] = acc[mt][nt][r];
}

// ---- per-(token, head) RMSNorm + RoPE on fused qkv (fp32) --------------
__global__ __launch_bounds__(64)
void norm_rope(float* __restrict__ qkv, const float* __restrict__ qw,
               const float* __restrict__ kw)
{
    const int s = blockIdx.x, hh = blockIdx.y, l = threadIdx.x;
    float* p; const float* wn; float scale;
    if (hh < NH) { p = qkv + (size_t)s * QS + hh * HD;               wn = qw; scale = 0.08838834764831845f; }
    else         { p = qkv + (size_t)s * QS + 2048 + (hh - NH) * HD; wn = kw; scale = 1.0f; }
    float x0 = p[l], x1 = p[l + 64];
    float ss = x0 * x0 + x1 * x1;
#pragma unroll
    for (int off = 32; off; off >>= 1) ss += __shfl_xor(ss, off);
    float inv = rsqrtf(ss * (1.0f / 128.0f) + 1e-6f);
    x0 *= inv * wn[l];
    x1 *= inv * wn[l + 64];
    float invf = exp2f(-(float)l * (13.287712379549449f / 64.0f));
    float ang  = (float)s * invf;
    float c, sn;
    sincosf(ang, &sn, &c);
    p[l]      = (x0 * c - x1 * sn) * scale;
    p[l + 64] = (x1 * c + x0 * sn) * scale;
}

// ---- MFMA flash attention, causal GQA. One 64-row q-tile per block. ----
// Grid 32x16, longest q-tiles dispatched first. Output written as bf16.
__global__ __launch_bounds__(256)
void attn_mfma(const float* __restrict__ qkv, __bf16* __restrict__ o)
{
    __shared__ __bf16 Ks[64 * 136];      // [key][dim]
    __shared__ __bf16 Vt[128 * 72];      // [dim][key], xor-swizzled pair cols
    __shared__ __bf16 Ps[4][16 * 72];    // per-wave P strip [q][key]

    const int tid = threadIdx.x, lane = tid & 63, w = tid >> 6;
    const int mm = lane & 15, quad = lane >> 4;
    const int h = blockIdx.y, kh = h >> 2;
    const int qt = 31 - blockIdx.x;      // big tiles first

    const float* kbase = qkv + 2048 + kh * HD;
    const float* vbase = qkv + 2560 + kh * HD;

    bf8v aq[4];
    const float* qbase = qkv + (size_t)(qt * 64 + w * 16 + mm) * QS + h * HD;
#pragma unroll
    for (int ks = 0; ks < 4; ++ks) {
        float4 f0 = *reinterpret_cast<const float4*>(qbase + ks * 32 + quad * 8);
        float4 f1 = *reinterpret_cast<const float4*>(qbase + ks * 32 + quad * 8 + 4);
        aq[ks] = bf8v{ (__bf16)f0.x, (__bf16)f0.y, (__bf16)f0.z, (__bf16)f0.w,
                       (__bf16)f1.x, (__bf16)f1.y, (__bf16)f1.z, (__bf16)f1.w };
    }

    float mrow[4], lrow[4];
    f4v oacc[8] = {};
#pragma unroll
    for (int r = 0; r < 4; ++r) { mrow[r] = -__builtin_inff(); lrow[r] = 0.f; }

    for (int kt = 0; kt <= qt; ++kt) {
        __syncthreads();
        // stage K tile (coalesced, bf16)
#pragma unroll
        for (int t = 0; t < 8; ++t) {
            int f = tid + t * 256;
            int row = f >> 5, c4 = (f & 31) * 4;
            float4 kv = *reinterpret_cast<const float4*>(&kbase[(size_t)(kt * 64 + row) * QS + c4]);
            *reinterpret_cast<bf4v*>(&Ks[row * 136 + c4]) =
                bf4v{ (__bf16)kv.x, (__bf16)kv.y, (__bf16)kv.z, (__bf16)kv.w };
        }
        // stage V transposed, swizzled pair columns
#pragma unroll
        for (int t = 0; t < 4; ++t) {
            int f  = tid + t * 256;
            int kp = f >> 5;
            int c4 = (f & 31) * 4;
            const float* vr = &vbase[(size_t)(kt * 64 + 2 * kp) * QS + c4];
            float4 v0 = *reinterpret_cast<const float4*>(vr);
            float4 v1 = *reinterpret_cast<const float4*>(vr + QS);
#pragma unroll
            for (int i = 0; i < 4; ++i) {
                int d   = c4 + i;
                int col = kp ^ (((d >> 2) & 7) << 2);
                float e0 = (i == 0) ? v0.x : (i == 1) ? v0.y : (i == 2) ? v0.z : v0.w;
                float e1 = (i == 0) ? v1.x : (i == 1) ? v1.y : (i == 2) ? v1.z : v1.w;
                *reinterpret_cast<bf2v*>(reinterpret_cast<char*>(Vt) + d * 144 + col * 4) =
                    bf2v{ (__bf16)e0, (__bf16)e1 };
            }
        }
        __syncthreads();

        // S = Q K^T
        f4v s[4] = {};
#pragma unroll
        for (int ks = 0; ks < 4; ++ks)
#pragma unroll
            for (int c = 0; c < 4; ++c) {
                bf8v b = *reinterpret_cast<const bf8v*>(&Ks[(c * 16 + mm) * 136 + ks * 32 + quad * 8]);
                s[c] = __builtin_amdgcn_mfma_f32_16x16x32_bf16(aq[ks], b, s[c], 0, 0, 0);
            }
        if (kt == qt) {
#pragma unroll
            for (int c = 0; c < 4; ++c)
#pragma unroll
                for (int r = 0; r < 4; ++r)
                    if (c * 16 + mm > w * 16 + quad * 4 + r)
                        s[c][r] = -__builtin_inff();
        }
        // online softmax
        float pr[4][4];
#pragma unroll
        for (int r = 0; r < 4; ++r) {
            float cm = fmaxf(fmaxf(s[0][r], s[1][r]), fmaxf(s[2][r], s[3][r]));
#pragma unroll
            for (int off = 8; off; off >>= 1) cm = fmaxf(cm, __shfl_xor(cm, off));
            float mnew  = fmaxf(mrow[r], cm);
            float alpha = __expf(mrow[r] - mnew);
            mrow[r] = mnew;
            float rs = 0.f;
#pragma unroll
            for (int c = 0; c < 4; ++c) { pr[c][r] = __expf(s[c][r] - mnew); rs += pr[c][r]; }
#pragma unroll
            for (int off = 8; off; off >>= 1) rs += __shfl_xor(rs, off);
            lrow[r] = lrow[r] * alpha + rs;
#pragma unroll
            for (int nb = 0; nb < 8; ++nb) oacc[nb][r] *= alpha;
        }
        // P strip: C-layout -> A-layout via wave-private LDS
#pragma unroll
        for (int c = 0; c < 4; ++c)
#pragma unroll
            for (int r = 0; r < 4; ++r) {
                float mine  = pr[c][r];
                float other = __shfl_xor(mine, 1);
                if ((mm & 1) == 0)
                    *reinterpret_cast<bf2v*>(
                        reinterpret_cast<char*>(&Ps[w][0]) + (quad * 4 + r) * 144 + (c * 16 + mm) * 2) =
                        bf2v{ (__bf16)mine, (__bf16)other };
            }
        bf8v pa[2];
#pragma unroll
        for (int kb = 0; kb < 2; ++kb)
            pa[kb] = *reinterpret_cast<const bf8v*>(
                reinterpret_cast<const char*>(&Ps[w][0]) + mm * 144 + kb * 64 + quad * 16);
#pragma unroll
        for (int nb = 0; nb < 8; ++nb) {
            int d  = nb * 16 + mm;
            int xr = ((d >> 2) & 7) << 2;
#pragma unroll
            for (int kb = 0; kb < 2; ++kb) {
                int gp = (kb * 16 + quad * 4) ^ xr;
                bf8v bv = *reinterpret_cast<const bf8v*>(
                    reinterpret_cast<const char*>(Vt) + d * 144 + gp * 4);
                oacc[nb] = __builtin_amdgcn_mfma_f32_16x16x32_bf16(pa[kb], bv, oacc[nb], 0, 0, 0);
            }
        }
    }
#pragma unroll
    for (int r = 0; r < 4; ++r) {
        float invl = 1.f / lrow[r];
        size_t row = (size_t)(qt * 64 + w * 16 + quad * 4 + r) * (NH * HD) + h * HD;
#pragma unroll
        for (int nb = 0; nb < 8; ++nb)
            o[row + nb * 16 + mm] = (__bf16)(oacc[nb][r] * invl);
    }
}

extern "C" void kernel_launch(void* const* d_in, const int* in_sizes, int n_in,
                              void* d_out, int out_size, void* d_ws, size_t ws_size,
                              hipStream_t stream)
{
    const float* hs  = (const float*)d_in[0];
    const float* mu  = (const float*)d_in[1];
    const float* wq  = (const float*)d_in[2];
    const float* wk  = (const float*)d_in[3];
    const float* wv  = (const float*)d_in[4];
    const float* wo  = (const float*)d_in[5];
    const float* wmq = (const float*)d_in[6];
    const float* wmk = (const float*)d_in[7];
    const float* wmv = (const float*)d_in[8];
    const float* qw  = (const float*)d_in[9];
    const float* kw  = (const float*)d_in[10];
    float* out = (float*)d_out;

    // workspace layout (bytes)
    char* ws = (char*)d_ws;
    __bf16* Wcat = (__bf16*)(ws + 0);                       // [3072, 4096] 25.2 MB
    __bf16* Acat = (__bf16*)(ws + 25165824);                // [2048, 4096] 16.8 MB
    __bf16* Wo   = (__bf16*)(ws + 41943040);                // [2048, 2048]  8.4 MB
    float*  qkv  = (float*) (ws + 50331648);                // [2048, 3072] 25.2 MB
    __bf16* ab   = (__bf16*)(ws + 75497472);                // [2048, 2048]  8.4 MB

    // fp32 -> bf16 packing (concat along K)
    cvt_cat2<<<dim3((2048 * 1024 + 255) / 256), 256, 0, stream>>>(Acat, hs, mu, 2048, 512);
    cvt_cat2<<<dim3((2048 * 1024 + 255) / 256), 256, 0, stream>>>(Wcat, wq, wmq, 2048, 512);
    cvt_cat2<<<dim3((512 * 1024 + 255) / 256), 256, 0, stream>>>(Wcat + (size_t)2048 * 4096, wk, wmk, 512, 512);
    cvt_cat2<<<dim3((512 * 1024 + 255) / 256), 256, 0, stream>>>(Wcat + (size_t)2560 * 4096, wv, wmv, 512, 512);
    cvt<<<dim3((1024 * 1024 + 255) / 256), 256, 0, stream>>>(Wo, wo, 1024 * 1024);

    // fused QKV projection: [2048, 3072] = Acat[2048,4096] . Wcat[3072,4096]^T
    gemm_nt<<<dim3(QS / 128, SEQ / 128), 256, 0, stream>>>(Acat, Wcat, qkv, SEQ, QS, 2 * HID_DIM);
    norm_rope<<<dim3(SEQ, NH + NKV), dim3(64), 0, stream>>>(qkv, qw, kw);
    attn_mfma<<<dim3(32, NH), 256, 0, stream>>>(qkv, ab);
    // output projection: out[2048,2048] = ab[2048,2048] . Wo[2048,2048]^T
    gemm_nt<<<dim3(HID_DIM / 128, SEQ / 128), 256, 0, stream>>>(ab, Wo, out, SEQ, HID_DIM, NH * HD);
}

// Round 4
// 433.513 us; speedup vs baseline: 5.7326x; 1.2167x over previous
//
#include <hip/hip_runtime.h>
#include <math.h>

#define SEQ 2048
#define HID_DIM 2048
#define NH 16
#define NKV 4
#define HD 128
#define QS 3072   // fused qkv row stride (floats): [q 2048 | k 512 | v 512]

typedef float  f4v  __attribute__((ext_vector_type(4)));
typedef __bf16 bf8v __attribute__((ext_vector_type(8)));
typedef __bf16 bf4v __attribute__((ext_vector_type(4)));
typedef __bf16 bf2v __attribute__((ext_vector_type(2)));

typedef __attribute__((address_space(1))) const void* gvp;
typedef __attribute__((address_space(3))) void*       svp;

__device__ __forceinline__ void gld16(const void* g, void* lds_wave_base) {
    __builtin_amdgcn_global_load_lds((gvp)g, (svp)lds_wave_base, 16, 0, 0);
}

// ---- fp32 -> bf16 converts ---------------------------------------------
__global__ __launch_bounds__(256)
void cvt_cat2(__bf16* __restrict__ dst, const float* __restrict__ s0,
              const float* __restrict__ s1, int rows, int kq)
{
    int i = blockIdx.x * 256 + threadIdx.x;
    if (i >= rows * kq * 2) return;
    int row = i / (2 * kq), c = i - row * 2 * kq;
    const float* s = (c < kq) ? s0 + ((size_t)row * kq + c) * 4
                              : s1 + ((size_t)row * kq + (c - kq)) * 4;
    float4 v = *reinterpret_cast<const float4*>(s);
    *reinterpret_cast<bf4v*>(dst + ((size_t)row * 2 * kq + c) * 4) =
        bf4v{ (__bf16)v.x, (__bf16)v.y, (__bf16)v.z, (__bf16)v.w };
}

__global__ __launch_bounds__(256)
void cvt(__bf16* __restrict__ dst, const float* __restrict__ src, int n4)
{
    int i = blockIdx.x * 256 + threadIdx.x;
    if (i >= n4) return;
    float4 v = *reinterpret_cast<const float4*>(src + (size_t)i * 4);
    *reinterpret_cast<bf4v*>(dst + (size_t)i * 4) =
        bf4v{ (__bf16)v.x, (__bf16)v.y, (__bf16)v.z, (__bf16)v.w };
}

// ---- m97-style NT GEMM: C[M,N] f32 = A[M,K] bf16 . B[N,K]^T bf16 -------
__global__ __launch_bounds__(256)
void gemm_nt(const __bf16* __restrict__ A, const __bf16* __restrict__ B,
             float* __restrict__ C, int M, int N, int K)
{
    __shared__ __bf16 As[128 * 32];
    __shared__ __bf16 Bs[128 * 32];
    const int tid = threadIdx.x, lane = tid & 63, w = tid >> 6;
    const int wm = w >> 1, wn = w & 1;
    const int mm = lane & 15, quad = lane >> 4;
    const int m0 = blockIdx.y * 128, n0 = blockIdx.x * 128;
    const int r0 = lane >> 2, c0 = (lane & 3) * 8;

    f4v acc[4][4] = {};

    for (int k0 = 0; k0 < K; k0 += 32) {
#pragma unroll
        for (int j = 0; j < 2; ++j) {
            int chunk = w * 2 + j;
            int row   = chunk * 16 + r0;
            gld16(&A[(size_t)(m0 + row) * K + k0 + c0], (char*)As + chunk * 1024);
            gld16(&B[(size_t)(n0 + row) * K + k0 + c0], (char*)Bs + chunk * 1024);
        }
        __syncthreads();
        bf8v af[4], bf[4];
#pragma unroll
        for (int t = 0; t < 4; ++t) {
            af[t] = *reinterpret_cast<const bf8v*>(&As[(wm * 64 + t * 16 + mm) * 32 + quad * 8]);
            bf[t] = *reinterpret_cast<const bf8v*>(&Bs[(wn * 64 + t * 16 + mm) * 32 + quad * 8]);
        }
#pragma unroll
        for (int mt = 0; mt < 4; ++mt)
#pragma unroll
            for (int nt = 0; nt < 4; ++nt)
                acc[mt][nt] = __builtin_amdgcn_mfma_f32_16x16x32_bf16(af[mt], bf[nt], acc[mt][nt], 0, 0, 0);
        __syncthreads();
    }
#pragma unroll
    for (int mt = 0; mt < 4; ++mt)
#pragma unroll
        for (int nt = 0; nt < 4; ++nt)
#pragma unroll
            for (int r = 0; r < 4; ++r)
                C[(size_t)(m0 + wm * 64 + mt * 16 + quad * 4 + r) * N
                  + n0 + wn * 64 + nt * 16 + mm] = acc[mt][nt][r];
}

// ---- per-(token, head) RMSNorm + RoPE on fused qkv (fp32, in place) ----
__global__ __launch_bounds__(64)
void norm_rope(float* __restrict__ qkv, const float* __restrict__ qw,
               const float* __restrict__ kw)
{
    const int s = blockIdx.x, hh = blockIdx.y, l = threadIdx.x;
    float* p; const float* wn; float scale;
    if (hh < NH) { p = qkv + (size_t)s * QS + hh * HD;               wn = qw; scale = 0.08838834764831845f; }
    else         { p = qkv + (size_t)s * QS + 2048 + (hh - NH) * HD; wn = kw; scale = 1.0f; }
    float x0 = p[l], x1 = p[l + 64];
    float ss = x0 * x0 + x1 * x1;
#pragma unroll
    for (int off = 32; off; off >>= 1) ss += __shfl_xor(ss, off);
    float inv = rsqrtf(ss * (1.0f / 128.0f) + 1e-6f);
    x0 *= inv * wn[l];
    x1 *= inv * wn[l + 64];
    float invf = exp2f(-(float)l * (13.287712379549449f / 64.0f));
    float ang  = (float)s * invf;
    float c, sn;
    sincosf(ang, &sn, &c);
    p[l]      = (x0 * c - x1 * sn) * scale;
    p[l + 64] = (x1 * c + x0 * sn) * scale;
}

// ---- pack K tiles: per (kh,kt) a 16 KB image == desired LDS image ------
// image offset = key*256 + pc*16, pc = c ^ (key&15), chunk c = dim/8
__global__ __launch_bounds__(256)
void pack_k(const float* __restrict__ qkv, __bf16* __restrict__ Kt)
{
    const int kt = blockIdx.x, kh = blockIdx.y, t = threadIdx.x;
    char* tile = (char*)Kt + ((size_t)(kh * 32 + kt)) * 16384;
    const float* src = qkv + 2048 + kh * HD;
#pragma unroll
    for (int i = 0; i < 4; ++i) {
        int cid = t * 4 + i;
        int key = cid >> 4, pc = cid & 15;
        int c = pc ^ (key & 15);
        const float* s = src + (size_t)(kt * 64 + key) * QS + c * 8;
        float4 a = *reinterpret_cast<const float4*>(s);
        float4 b = *reinterpret_cast<const float4*>(s + 4);
        *reinterpret_cast<bf8v*>(tile + cid * 16) =
            bf8v{ (__bf16)a.x, (__bf16)a.y, (__bf16)a.z, (__bf16)a.w,
                  (__bf16)b.x, (__bf16)b.y, (__bf16)b.z, (__bf16)b.w };
    }
}

// ---- pack V tiles transposed: image offset = d*128 + kcp*16 + j*2 ------
// content keys kc*8+j at dim d, kc = kcp ^ (d&7)
__global__ __launch_bounds__(256)
void pack_v(const float* __restrict__ qkv, __bf16* __restrict__ Vt)
{
    const int kt = blockIdx.x, kh = blockIdx.y, t = threadIdx.x;
    char* tile = (char*)Vt + ((size_t)(kh * 32 + kt)) * 16384;
    const float* src = qkv + 2560 + kh * HD;
#pragma unroll
    for (int i = 0; i < 4; ++i) {
        int cid = t * 4 + i;
        int d = cid >> 3, kcp = cid & 7;
        int kc = kcp ^ (d & 7);
        const float* s = src + (size_t)(kt * 64 + kc * 8) * QS + d;
        __bf16 tmp[8];
#pragma unroll
        for (int j = 0; j < 8; ++j) tmp[j] = (__bf16)s[(size_t)j * QS];
        *reinterpret_cast<bf8v*>(tile + cid * 16) = *reinterpret_cast<bf8v*>(tmp);
    }
}

// ---- split-K MFMA flash attention -------------------------------------
// grid (chunk c<4, qt<32, h<16); chunk covers k-tiles [8c, min(8c+7, qt)].
// Partials (unnormalized O bf16, m, l fp32) to scratch; combine pass merges.
__global__ __launch_bounds__(256)
void attn_split(const float* __restrict__ qkv,
                const __bf16* __restrict__ Kt, const __bf16* __restrict__ Vt,
                __bf16* __restrict__ Op, float* __restrict__ Mp, float* __restrict__ Lp)
{
    __shared__ char Ks[16384];    // [key][dim], xor-swizzled 16B chunks
    __shared__ char Vs[16384];    // [dim][key], xor-swizzled 16B chunks
    __shared__ __bf16 Ps[4][16 * 72];

    const int c = blockIdx.x, qt = blockIdx.y, h = blockIdx.z;
    if (c * 8 > qt) return;
    const int kend = min(qt, c * 8 + 7);
    const int tid = threadIdx.x, lane = tid & 63, w = tid >> 6;
    const int mm = lane & 15, quad = lane >> 4;
    const int kh = h >> 2;

    // Q fragments from fp32 qkv (once per block)
    bf8v aq[4];
    const float* qbase = qkv + (size_t)(qt * 64 + w * 16 + mm) * QS + h * HD;
#pragma unroll
    for (int ks = 0; ks < 4; ++ks) {
        float4 f0 = *reinterpret_cast<const float4*>(qbase + ks * 32 + quad * 8);
        float4 f1 = *reinterpret_cast<const float4*>(qbase + ks * 32 + quad * 8 + 4);
        aq[ks] = bf8v{ (__bf16)f0.x, (__bf16)f0.y, (__bf16)f0.z, (__bf16)f0.w,
                       (__bf16)f1.x, (__bf16)f1.y, (__bf16)f1.z, (__bf16)f1.w };
    }

    float mrow[4], lrow[4];
    f4v oacc[8] = {};
#pragma unroll
    for (int r = 0; r < 4; ++r) { mrow[r] = -__builtin_inff(); lrow[r] = 0.f; }

    for (int kt = c * 8; kt <= kend; ++kt) {
        __syncthreads();
        const char* ktile = (const char*)Kt + ((size_t)(kh * 32 + kt)) * 16384;
        const char* vtile = (const char*)Vt + ((size_t)(kh * 32 + kt)) * 16384;
#pragma unroll
        for (int j = 0; j < 4; ++j) {
            int chunk = w * 4 + j;          // 16 x 1 KiB chunks each
            gld16(ktile + chunk * 1024 + lane * 16, Ks + chunk * 1024);
            gld16(vtile + chunk * 1024 + lane * 16, Vs + chunk * 1024);
        }
        __syncthreads();

        // S = Q K^T ; K frag: key=c16*16+mm, pc = (ks*4+quad) ^ mm
        f4v s[4] = {};
#pragma unroll
        for (int ks = 0; ks < 4; ++ks)
#pragma unroll
            for (int c16 = 0; c16 < 4; ++c16) {
                bf8v b = *reinterpret_cast<const bf8v*>(
                    Ks + (c16 * 16 + mm) * 256 + (((ks * 4 + quad) ^ mm) << 4));
                s[c16] = __builtin_amdgcn_mfma_f32_16x16x32_bf16(aq[ks], b, s[c16], 0, 0, 0);
            }
        if (kt == qt) {
#pragma unroll
            for (int c16 = 0; c16 < 4; ++c16)
#pragma unroll
                for (int r = 0; r < 4; ++r)
                    if (c16 * 16 + mm > w * 16 + quad * 4 + r)
                        s[c16][r] = -__builtin_inff();
        }
        // online softmax
        float pr[4][4];
#pragma unroll
        for (int r = 0; r < 4; ++r) {
            float cm = fmaxf(fmaxf(s[0][r], s[1][r]), fmaxf(s[2][r], s[3][r]));
#pragma unroll
            for (int off = 8; off; off >>= 1) cm = fmaxf(cm, __shfl_xor(cm, off));
            float mnew  = fmaxf(mrow[r], cm);
            float alpha = __expf(mrow[r] - mnew);
            mrow[r] = mnew;
            float rs = 0.f;
#pragma unroll
            for (int c16 = 0; c16 < 4; ++c16) { pr[c16][r] = __expf(s[c16][r] - mnew); rs += pr[c16][r]; }
#pragma unroll
            for (int off = 8; off; off >>= 1) rs += __shfl_xor(rs, off);
            lrow[r] = lrow[r] * alpha + rs;
#pragma unroll
            for (int nb = 0; nb < 8; ++nb) oacc[nb][r] *= alpha;
        }
        // P strip: C-layout -> A-layout via wave-private LDS
#pragma unroll
        for (int c16 = 0; c16 < 4; ++c16)
#pragma unroll
            for (int r = 0; r < 4; ++r) {
                float mine  = pr[c16][r];
                float other = __shfl_xor(mine, 1);
                if ((mm & 1) == 0)
                    *reinterpret_cast<bf2v*>(
                        reinterpret_cast<char*>(&Ps[w][0]) + (quad * 4 + r) * 144 + (c16 * 16 + mm) * 2) =
                        bf2v{ (__bf16)mine, (__bf16)other };
            }
        bf8v pa[2];
#pragma unroll
        for (int kb = 0; kb < 2; ++kb)
            pa[kb] = *reinterpret_cast<const bf8v*>(
                reinterpret_cast<const char*>(&Ps[w][0]) + mm * 144 + kb * 64 + quad * 16);
        // O += P V ; V frag: d=nb*16+mm, kcp = (kb*4+quad) ^ (d&7)
#pragma unroll
        for (int nb = 0; nb < 8; ++nb) {
            int d = nb * 16 + mm;
#pragma unroll
            for (int kb = 0; kb < 2; ++kb) {
                bf8v bv = *reinterpret_cast<const bf8v*>(
                    Vs + d * 128 + (((kb * 4 + quad) ^ (d & 7)) << 4));
                oacc[nb] = __builtin_amdgcn_mfma_f32_16x16x32_bf16(pa[kb], bv, oacc[nb], 0, 0, 0);
            }
        }
    }
    // epilogue: unnormalized partials
#pragma unroll
    for (int r = 0; r < 4; ++r) {
        int row = qt * 64 + w * 16 + quad * 4 + r;
        size_t obase = ((size_t)(c * 16 + h) * SEQ + row) * HD;
#pragma unroll
        for (int nb = 0; nb < 8; ++nb)
            Op[obase + nb * 16 + mm] = (__bf16)oacc[nb][r];
        if (mm == 0) {
            Mp[(size_t)(c * 16 + h) * SEQ + row] = mrow[r];
            Lp[(size_t)(c * 16 + h) * SEQ + row] = lrow[r];
        }
    }
}

// ---- combine split-K partials -> ab (bf16 [row][h*128+d]) --------------
__global__ __launch_bounds__(64)
void combine(const __bf16* __restrict__ Op, const float* __restrict__ Mp,
             const float* __restrict__ Lp, __bf16* __restrict__ ab)
{
    const int row = blockIdx.x, h = blockIdx.y, l = threadIdx.x;
    const int nch = (row >> 9) + 1;
    float mv[4], M = -__builtin_inff();
    for (int c = 0; c < nch; ++c) {
        mv[c] = Mp[(size_t)(c * 16 + h) * SEQ + row];
        M = fmaxf(M, mv[c]);
    }
    float L = 0.f, a0 = 0.f, a1 = 0.f;
    for (int c = 0; c < nch; ++c) {
        float wgt = __expf(mv[c] - M);
        L += Lp[(size_t)(c * 16 + h) * SEQ + row] * wgt;
        bf2v p = *reinterpret_cast<const bf2v*>(
            Op + ((size_t)(c * 16 + h) * SEQ + row) * HD + 2 * l);
        a0 += wgt * (float)p[0];
        a1 += wgt * (float)p[1];
    }
    float inv = 1.f / L;
    *reinterpret_cast<bf2v*>(ab + (size_t)row * (NH * HD) + h * HD + 2 * l) =
        bf2v{ (__bf16)(a0 * inv), (__bf16)(a1 * inv) };
}

extern "C" void kernel_launch(void* const* d_in, const int* in_sizes, int n_in,
                              void* d_out, int out_size, void* d_ws, size_t ws_size,
                              hipStream_t stream)
{
    const float* hs  = (const float*)d_in[0];
    const float* mu  = (const float*)d_in[1];
    const float* wq  = (const float*)d_in[2];
    const float* wk  = (const float*)d_in[3];
    const float* wv  = (const float*)d_in[4];
    const float* wo  = (const float*)d_in[5];
    const float* wmq = (const float*)d_in[6];
    const float* wmk = (const float*)d_in[7];
    const float* wmv = (const float*)d_in[8];
    const float* qw  = (const float*)d_in[9];
    const float* kw  = (const float*)d_in[10];
    float* out = (float*)d_out;

    char* ws = (char*)d_ws;
    // phase-1 region [0, 41.9 MB): bf16 GEMM operands
    __bf16* Wcat = (__bf16*)(ws + 0);          // [3072,4096] 25.2 MB
    __bf16* Acat = (__bf16*)(ws + 25165824);   // [2048,4096] 16.8 MB
    // persistent
    __bf16* Wo   = (__bf16*)(ws + 41943040);   // [2048,2048]  8.4 MB
    float*  qkv  = (float*) (ws + 50331648);   // [2048,3072] 25.2 MB
    __bf16* ab   = (__bf16*)(ws + 75497472);   // [2048,2048]  8.4 MB
    // phase-2 aliases of phase-1 region (Wcat/Acat dead after qkv GEMM)
    __bf16* Ktl  = (__bf16*)(ws + 0);          // 2 MB
    __bf16* Vtl  = (__bf16*)(ws + 2097152);    // 2 MB
    __bf16* Opart= (__bf16*)(ws + 4194304);    // 32 MB
    float*  Mpart= (float*) (ws + 37748736);   // 0.5 MB
    float*  Lpart= (float*) (ws + 38273024);   // 0.5 MB

    cvt_cat2<<<dim3((2048 * 1024 + 255) / 256), 256, 0, stream>>>(Acat, hs, mu, 2048, 512);
    cvt_cat2<<<dim3((2048 * 1024 + 255) / 256), 256, 0, stream>>>(Wcat, wq, wmq, 2048, 512);
    cvt_cat2<<<dim3((512 * 1024 + 255) / 256), 256, 0, stream>>>(Wcat + (size_t)2048 * 4096, wk, wmk, 512, 512);
    cvt_cat2<<<dim3((512 * 1024 + 255) / 256), 256, 0, stream>>>(Wcat + (size_t)2560 * 4096, wv, wmv, 512, 512);
    cvt<<<dim3((1024 * 1024 + 255) / 256), 256, 0, stream>>>(Wo, wo, 1024 * 1024);

    gemm_nt<<<dim3(QS / 128, SEQ / 128), 256, 0, stream>>>(Acat, Wcat, qkv, SEQ, QS, 2 * HID_DIM);
    norm_rope<<<dim3(SEQ, NH + NKV), dim3(64), 0, stream>>>(qkv, qw, kw);
    pack_k<<<dim3(32, NKV), 256, 0, stream>>>(qkv, Ktl);
    pack_v<<<dim3(32, NKV), 256, 0, stream>>>(qkv, Vtl);
    attn_split<<<dim3(4, 32, NH), 256, 0, stream>>>(qkv, Ktl, Vtl, Opart, Mpart, Lpart);
    combine<<<dim3(SEQ, NH), 64, 0, stream>>>(Opart, Mpart, Lpart, ab);
    gemm_nt<<<dim3(HID_DIM / 128, SEQ / 128), 256, 0, stream>>>(ab, Wo, out, SEQ, HID_DIM, NH * HD);
}

// Round 5
// 409.022 us; speedup vs baseline: 6.0758x; 1.0599x over previous
//
#include <hip/hip_runtime.h>
#include <math.h>

#define SEQ 2048
#define HID_DIM 2048
#define NH 16
#define NKV 4
#define HD 128
#define QS 3072   // fused qkv row stride (floats): [q 2048 | k 512 | v 512]

typedef float  f4v  __attribute__((ext_vector_type(4)));
typedef __bf16 bf8v __attribute__((ext_vector_type(8)));
typedef __bf16 bf4v __attribute__((ext_vector_type(4)));
typedef __bf16 bf2v __attribute__((ext_vector_type(2)));

typedef __attribute__((address_space(1))) const void* gvp;
typedef __attribute__((address_space(3))) void*       svp;

__device__ __forceinline__ void gld16(const void* g, void* lds_wave_base) {
    __builtin_amdgcn_global_load_lds((gvp)g, (svp)lds_wave_base, 16, 0, 0);
}

// ---- fp32 -> bf16 converts ---------------------------------------------
__global__ __launch_bounds__(256)
void cvt_cat2(__bf16* __restrict__ dst, const float* __restrict__ s0,
              const float* __restrict__ s1, int rows, int kq)
{
    int i = blockIdx.x * 256 + threadIdx.x;
    if (i >= rows * kq * 2) return;
    int row = i / (2 * kq), c = i - row * 2 * kq;
    const float* s = (c < kq) ? s0 + ((size_t)row * kq + c) * 4
                              : s1 + ((size_t)row * kq + (c - kq)) * 4;
    float4 v = *reinterpret_cast<const float4*>(s);
    *reinterpret_cast<bf4v*>(dst + ((size_t)row * 2 * kq + c) * 4) =
        bf4v{ (__bf16)v.x, (__bf16)v.y, (__bf16)v.z, (__bf16)v.w };
}

__global__ __launch_bounds__(256)
void cvt(__bf16* __restrict__ dst, const float* __restrict__ src, int n4)
{
    int i = blockIdx.x * 256 + threadIdx.x;
    if (i >= n4) return;
    float4 v = *reinterpret_cast<const float4*>(src + (size_t)i * 4);
    *reinterpret_cast<bf4v*>(dst + (size_t)i * 4) =
        bf4v{ (__bf16)v.x, (__bf16)v.y, (__bf16)v.z, (__bf16)v.w };
}

// ---- NT GEMM, 128x64 tile: C[M,N] f32 = A[M,K] bf16 . B[N,K]^T bf16 ----
// BK=32, 256 thr = 4 waves (2m x 2n), wave tile 64x32 (8 MFMA, 6 ds_read,
// 3 gld16). Smaller tile -> more blocks -> 2-3 blocks/CU for latency overlap.
__global__ __launch_bounds__(256)
void gemm_nt(const __bf16* __restrict__ A, const __bf16* __restrict__ B,
             float* __restrict__ C, int M, int N, int K)
{
    __shared__ __bf16 As[128 * 32];
    __shared__ __bf16 Bs[64 * 32];
    const int tid = threadIdx.x, lane = tid & 63, w = tid >> 6;
    const int wm = w >> 1, wn = w & 1;
    const int mm = lane & 15, quad = lane >> 4;
    const int m0 = blockIdx.y * 128, n0 = blockIdx.x * 64;
    const int r0 = lane >> 2, c0 = (lane & 3) * 8;

    f4v acc[4][2] = {};

    for (int k0 = 0; k0 < K; k0 += 32) {
        // stage A: 8 chunks of 1 KiB (wave w -> chunks 2w, 2w+1)
#pragma unroll
        for (int j = 0; j < 2; ++j) {
            int chunk = w * 2 + j;
            gld16(&A[(size_t)(m0 + chunk * 16 + r0) * K + k0 + c0], (char*)As + chunk * 1024);
        }
        // stage B: 4 chunks (wave w -> chunk w)
        gld16(&B[(size_t)(n0 + w * 16 + r0) * K + k0 + c0], (char*)Bs + w * 1024);
        __syncthreads();
        bf8v af[4], bfv[2];
#pragma unroll
        for (int t = 0; t < 4; ++t)
            af[t] = *reinterpret_cast<const bf8v*>(&As[(wm * 64 + t * 16 + mm) * 32 + quad * 8]);
#pragma unroll
        for (int n = 0; n < 2; ++n)
            bfv[n] = *reinterpret_cast<const bf8v*>(&Bs[(wn * 32 + n * 16 + mm) * 32 + quad * 8]);
#pragma unroll
        for (int mt = 0; mt < 4; ++mt)
#pragma unroll
            for (int nt = 0; nt < 2; ++nt)
                acc[mt][nt] = __builtin_amdgcn_mfma_f32_16x16x32_bf16(af[mt], bfv[nt], acc[mt][nt], 0, 0, 0);
        __syncthreads();
    }
#pragma unroll
    for (int mt = 0; mt < 4; ++mt)
#pragma unroll
        for (int nt = 0; nt < 2; ++nt)
#pragma unroll
            for (int r = 0; r < 4; ++r)
                C[(size_t)(m0 + wm * 64 + mt * 16 + quad * 4 + r) * N
                  + n0 + wn * 32 + nt * 16 + mm] = acc[mt][nt][r];
}

// ---- per-(token, head) RMSNorm + RoPE on fused qkv (fp32, in place) ----
__global__ __launch_bounds__(64)
void norm_rope(float* __restrict__ qkv, const float* __restrict__ qw,
               const float* __restrict__ kw)
{
    const int s = blockIdx.x, hh = blockIdx.y, l = threadIdx.x;
    float* p; const float* wn; float scale;
    if (hh < NH) { p = qkv + (size_t)s * QS + hh * HD;               wn = qw; scale = 0.08838834764831845f; }
    else         { p = qkv + (size_t)s * QS + 2048 + (hh - NH) * HD; wn = kw; scale = 1.0f; }
    float x0 = p[l], x1 = p[l + 64];
    float ss = x0 * x0 + x1 * x1;
#pragma unroll
    for (int off = 32; off; off >>= 1) ss += __shfl_xor(ss, off);
    float inv = rsqrtf(ss * (1.0f / 128.0f) + 1e-6f);
    x0 *= inv * wn[l];
    x1 *= inv * wn[l + 64];
    float invf = exp2f(-(float)l * (13.287712379549449f / 64.0f));
    float ang  = (float)s * invf;
    float c, sn;
    sincosf(ang, &sn, &c);
    p[l]      = (x0 * c - x1 * sn) * scale;
    p[l + 64] = (x1 * c + x0 * sn) * scale;
}

// ---- pack K tiles: per (kh,kt) a 16 KB image == desired LDS image ------
// image offset = key*256 + pc*16, pc = c ^ (key&15), chunk c = dim/8
__global__ __launch_bounds__(256)
void pack_k(const float* __restrict__ qkv, __bf16* __restrict__ Kt)
{
    const int kt = blockIdx.x, kh = blockIdx.y, t = threadIdx.x;
    char* tile = (char*)Kt + ((size_t)(kh * 32 + kt)) * 16384;
    const float* src = qkv + 2048 + kh * HD;
#pragma unroll
    for (int i = 0; i < 4; ++i) {
        int cid = t * 4 + i;
        int key = cid >> 4, pc = cid & 15;
        int c = pc ^ (key & 15);
        const float* s = src + (size_t)(kt * 64 + key) * QS + c * 8;
        float4 a = *reinterpret_cast<const float4*>(s);
        float4 b = *reinterpret_cast<const float4*>(s + 4);
        *reinterpret_cast<bf8v*>(tile + cid * 16) =
            bf8v{ (__bf16)a.x, (__bf16)a.y, (__bf16)a.z, (__bf16)a.w,
                  (__bf16)b.x, (__bf16)b.y, (__bf16)b.z, (__bf16)b.w };
    }
}

// ---- pack V tiles transposed: image offset = d*128 + kcp*16 + j*2 ------
__global__ __launch_bounds__(256)
void pack_v(const float* __restrict__ qkv, __bf16* __restrict__ Vt)
{
    const int kt = blockIdx.x, kh = blockIdx.y, t = threadIdx.x;
    char* tile = (char*)Vt + ((size_t)(kh * 32 + kt)) * 16384;
    const float* src = qkv + 2560 + kh * HD;
#pragma unroll
    for (int i = 0; i < 4; ++i) {
        int cid = t * 4 + i;
        int d = cid >> 3, kcp = cid & 7;
        int kc = kcp ^ (d & 7);
        const float* s = src + (size_t)(kt * 64 + kc * 8) * QS + d;
        __bf16 tmp[8];
#pragma unroll
        for (int j = 0; j < 8; ++j) tmp[j] = (__bf16)s[(size_t)j * QS];
        *reinterpret_cast<bf8v*>(tile + cid * 16) = *reinterpret_cast<bf8v*>(tmp);
    }
}

// ---- split-K MFMA flash attention -------------------------------------
__global__ __launch_bounds__(256)
void attn_split(const float* __restrict__ qkv,
                const __bf16* __restrict__ Kt, const __bf16* __restrict__ Vt,
                __bf16* __restrict__ Op, float* __restrict__ Mp, float* __restrict__ Lp)
{
    __shared__ char Ks[16384];
    __shared__ char Vs[16384];
    __shared__ __bf16 Ps[4][16 * 72];

    const int c = blockIdx.x, qt = blockIdx.y, h = blockIdx.z;
    if (c * 8 > qt) return;
    const int kend = min(qt, c * 8 + 7);
    const int tid = threadIdx.x, lane = tid & 63, w = tid >> 6;
    const int mm = lane & 15, quad = lane >> 4;
    const int kh = h >> 2;

    bf8v aq[4];
    const float* qbase = qkv + (size_t)(qt * 64 + w * 16 + mm) * QS + h * HD;
#pragma unroll
    for (int ks = 0; ks < 4; ++ks) {
        float4 f0 = *reinterpret_cast<const float4*>(qbase + ks * 32 + quad * 8);
        float4 f1 = *reinterpret_cast<const float4*>(qbase + ks * 32 + quad * 8 + 4);
        aq[ks] = bf8v{ (__bf16)f0.x, (__bf16)f0.y, (__bf16)f0.z, (__bf16)f0.w,
                       (__bf16)f1.x, (__bf16)f1.y, (__bf16)f1.z, (__bf16)f1.w };
    }

    float mrow[4], lrow[4];
    f4v oacc[8] = {};
#pragma unroll
    for (int r = 0; r < 4; ++r) { mrow[r] = -__builtin_inff(); lrow[r] = 0.f; }

    for (int kt = c * 8; kt <= kend; ++kt) {
        __syncthreads();
        const char* ktile = (const char*)Kt + ((size_t)(kh * 32 + kt)) * 16384;
        const char* vtile = (const char*)Vt + ((size_t)(kh * 32 + kt)) * 16384;
#pragma unroll
        for (int j = 0; j < 4; ++j) {
            int chunk = w * 4 + j;
            gld16(ktile + chunk * 1024 + lane * 16, Ks + chunk * 1024);
            gld16(vtile + chunk * 1024 + lane * 16, Vs + chunk * 1024);
        }
        __syncthreads();

        f4v s[4] = {};
#pragma unroll
        for (int ks = 0; ks < 4; ++ks)
#pragma unroll
            for (int c16 = 0; c16 < 4; ++c16) {
                bf8v b = *reinterpret_cast<const bf8v*>(
                    Ks + (c16 * 16 + mm) * 256 + (((ks * 4 + quad) ^ mm) << 4));
                s[c16] = __builtin_amdgcn_mfma_f32_16x16x32_bf16(aq[ks], b, s[c16], 0, 0, 0);
            }
        if (kt == qt) {
#pragma unroll
            for (int c16 = 0; c16 < 4; ++c16)
#pragma unroll
                for (int r = 0; r < 4; ++r)
                    if (c16 * 16 + mm > w * 16 + quad * 4 + r)
                        s[c16][r] = -__builtin_inff();
        }
        float pr[4][4];
#pragma unroll
        for (int r = 0; r < 4; ++r) {
            float cm = fmaxf(fmaxf(s[0][r], s[1][r]), fmaxf(s[2][r], s[3][r]));
#pragma unroll
            for (int off = 8; off; off >>= 1) cm = fmaxf(cm, __shfl_xor(cm, off));
            float mnew  = fmaxf(mrow[r], cm);
            float alpha = __expf(mrow[r] - mnew);
            mrow[r] = mnew;
            float rs = 0.f;
#pragma unroll
            for (int c16 = 0; c16 < 4; ++c16) { pr[c16][r] = __expf(s[c16][r] - mnew); rs += pr[c16][r]; }
#pragma unroll
            for (int off = 8; off; off >>= 1) rs += __shfl_xor(rs, off);
            lrow[r] = lrow[r] * alpha + rs;
#pragma unroll
            for (int nb = 0; nb < 8; ++nb) oacc[nb][r] *= alpha;
        }
#pragma unroll
        for (int c16 = 0; c16 < 4; ++c16)
#pragma unroll
            for (int r = 0; r < 4; ++r) {
                float mine  = pr[c16][r];
                float other = __shfl_xor(mine, 1);
                if ((mm & 1) == 0)
                    *reinterpret_cast<bf2v*>(
                        reinterpret_cast<char*>(&Ps[w][0]) + (quad * 4 + r) * 144 + (c16 * 16 + mm) * 2) =
                        bf2v{ (__bf16)mine, (__bf16)other };
            }
        bf8v pa[2];
#pragma unroll
        for (int kb = 0; kb < 2; ++kb)
            pa[kb] = *reinterpret_cast<const bf8v*>(
                reinterpret_cast<const char*>(&Ps[w][0]) + mm * 144 + kb * 64 + quad * 16);
#pragma unroll
        for (int nb = 0; nb < 8; ++nb) {
            int d = nb * 16 + mm;
#pragma unroll
            for (int kb = 0; kb < 2; ++kb) {
                bf8v bv = *reinterpret_cast<const bf8v*>(
                    Vs + d * 128 + (((kb * 4 + quad) ^ (d & 7)) << 4));
                oacc[nb] = __builtin_amdgcn_mfma_f32_16x16x32_bf16(pa[kb], bv, oacc[nb], 0, 0, 0);
            }
        }
    }
#pragma unroll
    for (int r = 0; r < 4; ++r) {
        int row = qt * 64 + w * 16 + quad * 4 + r;
        size_t obase = ((size_t)(c * 16 + h) * SEQ + row) * HD;
#pragma unroll
        for (int nb = 0; nb < 8; ++nb)
            Op[obase + nb * 16 + mm] = (__bf16)oacc[nb][r];
        if (mm == 0) {
            Mp[(size_t)(c * 16 + h) * SEQ + row] = mrow[r];
            Lp[(size_t)(c * 16 + h) * SEQ + row] = lrow[r];
        }
    }
}

// ---- combine split-K partials -> ab (bf16 [row][h*128+d]) --------------
__global__ __launch_bounds__(64)
void combine(const __bf16* __restrict__ Op, const float* __restrict__ Mp,
             const float* __restrict__ Lp, __bf16* __restrict__ ab)
{
    const int row = blockIdx.x, h = blockIdx.y, l = threadIdx.x;
    const int nch = (row >> 9) + 1;
    float mv[4], M = -__builtin_inff();
    for (int c = 0; c < nch; ++c) {
        mv[c] = Mp[(size_t)(c * 16 + h) * SEQ + row];
        M = fmaxf(M, mv[c]);
    }
    float L = 0.f, a0 = 0.f, a1 = 0.f;
    for (int c = 0; c < nch; ++c) {
        float wgt = __expf(mv[c] - M);
        L += Lp[(size_t)(c * 16 + h) * SEQ + row] * wgt;
        bf2v p = *reinterpret_cast<const bf2v*>(
            Op + ((size_t)(c * 16 + h) * SEQ + row) * HD + 2 * l);
        a0 += wgt * (float)p[0];
        a1 += wgt * (float)p[1];
    }
    float inv = 1.f / L;
    *reinterpret_cast<bf2v*>(ab + (size_t)row * (NH * HD) + h * HD + 2 * l) =
        bf2v{ (__bf16)(a0 * inv), (__bf16)(a1 * inv) };
}

extern "C" void kernel_launch(void* const* d_in, const int* in_sizes, int n_in,
                              void* d_out, int out_size, void* d_ws, size_t ws_size,
                              hipStream_t stream)
{
    const float* hs  = (const float*)d_in[0];
    const float* mu  = (const float*)d_in[1];
    const float* wq  = (const float*)d_in[2];
    const float* wk  = (const float*)d_in[3];
    const float* wv  = (const float*)d_in[4];
    const float* wo  = (const float*)d_in[5];
    const float* wmq = (const float*)d_in[6];
    const float* wmk = (const float*)d_in[7];
    const float* wmv = (const float*)d_in[8];
    const float* qw  = (const float*)d_in[9];
    const float* kw  = (const float*)d_in[10];
    float* out = (float*)d_out;

    char* ws = (char*)d_ws;
    __bf16* Wcat = (__bf16*)(ws + 0);          // [3072,4096] 25.2 MB
    __bf16* Acat = (__bf16*)(ws + 25165824);   // [2048,4096] 16.8 MB
    __bf16* Wo   = (__bf16*)(ws + 41943040);   // [2048,2048]  8.4 MB
    float*  qkv  = (float*) (ws + 50331648);   // [2048,3072] 25.2 MB
    __bf16* ab   = (__bf16*)(ws + 75497472);   // [2048,2048]  8.4 MB
    __bf16* Ktl  = (__bf16*)(ws + 0);          // 2 MB (aliases dead Wcat)
    __bf16* Vtl  = (__bf16*)(ws + 2097152);    // 2 MB
    __bf16* Opart= (__bf16*)(ws + 4194304);    // 32 MB
    float*  Mpart= (float*) (ws + 37748736);   // 0.5 MB
    float*  Lpart= (float*) (ws + 38273024);   // 0.5 MB

    cvt_cat2<<<dim3((2048 * 1024 + 255) / 256), 256, 0, stream>>>(Acat, hs, mu, 2048, 512);
    cvt_cat2<<<dim3((2048 * 1024 + 255) / 256), 256, 0, stream>>>(Wcat, wq, wmq, 2048, 512);
    cvt_cat2<<<dim3((512 * 1024 + 255) / 256), 256, 0, stream>>>(Wcat + (size_t)2048 * 4096, wk, wmk, 512, 512);
    cvt_cat2<<<dim3((512 * 1024 + 255) / 256), 256, 0, stream>>>(Wcat + (size_t)2560 * 4096, wv, wmv, 512, 512);
    cvt<<<dim3((1024 * 1024 + 255) / 256), 256, 0, stream>>>(Wo, wo, 1024 * 1024);

    // fused QKV projection: grid 48x16 = 768 blocks = 3/CU
    gemm_nt<<<dim3(QS / 64, SEQ / 128), 256, 0, stream>>>(Acat, Wcat, qkv, SEQ, QS, 2 * HID_DIM);
    norm_rope<<<dim3(SEQ, NH + NKV), dim3(64), 0, stream>>>(qkv, qw, kw);
    pack_k<<<dim3(32, NKV), 256, 0, stream>>>(qkv, Ktl);
    pack_v<<<dim3(32, NKV), 256, 0, stream>>>(qkv, Vtl);
    attn_split<<<dim3(4, 32, NH), 256, 0, stream>>>(qkv, Ktl, Vtl, Opart, Mpart, Lpart);
    combine<<<dim3(SEQ, NH), 64, 0, stream>>>(Opart, Mpart, Lpart, ab);
    // output projection: grid 32x16 = 512 blocks = 2/CU
    gemm_nt<<<dim3(HID_DIM / 64, SEQ / 128), 256, 0, stream>>>(ab, Wo, out, SEQ, HID_DIM, NH * HD);
}

// Round 6
// 382.516 us; speedup vs baseline: 6.4969x; 1.0693x over previous
//
#include <hip/hip_runtime.h>
#include <math.h>

#define SEQ 2048
#define HID_DIM 2048
#define NH 16
#define NKV 4
#define HD 128
#define QS 3072   // fused qkv row stride (floats): [q 2048 | k 512 | v 512]

typedef float  f4v  __attribute__((ext_vector_type(4)));
typedef __bf16 bf8v __attribute__((ext_vector_type(8)));
typedef __bf16 bf4v __attribute__((ext_vector_type(4)));
typedef __bf16 bf2v __attribute__((ext_vector_type(2)));

typedef __attribute__((address_space(1))) const void* gvp;
typedef __attribute__((address_space(3))) void*       svp;

__device__ __forceinline__ void gld16(const void* g, void* lds_wave_base) {
    __builtin_amdgcn_global_load_lds((gvp)g, (svp)lds_wave_base, 16, 0, 0);
}

// ---- fp32 -> bf16 converts ---------------------------------------------
__global__ __launch_bounds__(256)
void cvt_cat2(__bf16* __restrict__ dst, const float* __restrict__ s0,
              const float* __restrict__ s1, int rows, int kq)
{
    int i = blockIdx.x * 256 + threadIdx.x;
    if (i >= rows * kq * 2) return;
    int row = i / (2 * kq), c = i - row * 2 * kq;
    const float* s = (c < kq) ? s0 + ((size_t)row * kq + c) * 4
                              : s1 + ((size_t)row * kq + (c - kq)) * 4;
    float4 v = *reinterpret_cast<const float4*>(s);
    *reinterpret_cast<bf4v*>(dst + ((size_t)row * 2 * kq + c) * 4) =
        bf4v{ (__bf16)v.x, (__bf16)v.y, (__bf16)v.z, (__bf16)v.w };
}

__global__ __launch_bounds__(256)
void cvt(__bf16* __restrict__ dst, const float* __restrict__ src, int n4)
{
    int i = blockIdx.x * 256 + threadIdx.x;
    if (i >= n4) return;
    float4 v = *reinterpret_cast<const float4*>(src + (size_t)i * 4);
    *reinterpret_cast<bf4v*>(dst + (size_t)i * 4) =
        bf4v{ (__bf16)v.x, (__bf16)v.y, (__bf16)v.z, (__bf16)v.w };
}

// ---- NT GEMM, 128x64 tile (unchanged from round 5) ---------------------
__global__ __launch_bounds__(256)
void gemm_nt(const __bf16* __restrict__ A, const __bf16* __restrict__ B,
             float* __restrict__ C, int M, int N, int K)
{
    __shared__ __bf16 As[128 * 32];
    __shared__ __bf16 Bs[64 * 32];
    const int tid = threadIdx.x, lane = tid & 63, w = tid >> 6;
    const int wm = w >> 1, wn = w & 1;
    const int mm = lane & 15, quad = lane >> 4;
    const int m0 = blockIdx.y * 128, n0 = blockIdx.x * 64;
    const int r0 = lane >> 2, c0 = (lane & 3) * 8;

    f4v acc[4][2] = {};

    for (int k0 = 0; k0 < K; k0 += 32) {
#pragma unroll
        for (int j = 0; j < 2; ++j) {
            int chunk = w * 2 + j;
            gld16(&A[(size_t)(m0 + chunk * 16 + r0) * K + k0 + c0], (char*)As + chunk * 1024);
        }
        gld16(&B[(size_t)(n0 + w * 16 + r0) * K + k0 + c0], (char*)Bs + w * 1024);
        __syncthreads();
        bf8v af[4], bfv[2];
#pragma unroll
        for (int t = 0; t < 4; ++t)
            af[t] = *reinterpret_cast<const bf8v*>(&As[(wm * 64 + t * 16 + mm) * 32 + quad * 8]);
#pragma unroll
        for (int n = 0; n < 2; ++n)
            bfv[n] = *reinterpret_cast<const bf8v*>(&Bs[(wn * 32 + n * 16 + mm) * 32 + quad * 8]);
#pragma unroll
        for (int mt = 0; mt < 4; ++mt)
#pragma unroll
            for (int nt = 0; nt < 2; ++nt)
                acc[mt][nt] = __builtin_amdgcn_mfma_f32_16x16x32_bf16(af[mt], bfv[nt], acc[mt][nt], 0, 0, 0);
        __syncthreads();
    }
#pragma unroll
    for (int mt = 0; mt < 4; ++mt)
#pragma unroll
        for (int nt = 0; nt < 2; ++nt)
#pragma unroll
            for (int r = 0; r < 4; ++r)
                C[(size_t)(m0 + wm * 64 + mt * 16 + quad * 4 + r) * N
                  + n0 + wn * 32 + nt * 16 + mm] = acc[mt][nt][r];
}

// ---- per-(token, head) RMSNorm + RoPE on fused qkv (fp32, in place) ----
__global__ __launch_bounds__(64)
void norm_rope(float* __restrict__ qkv, const float* __restrict__ qw,
               const float* __restrict__ kw)
{
    const int s = blockIdx.x, hh = blockIdx.y, l = threadIdx.x;
    float* p; const float* wn; float scale;
    if (hh < NH) { p = qkv + (size_t)s * QS + hh * HD;               wn = qw; scale = 0.08838834764831845f; }
    else         { p = qkv + (size_t)s * QS + 2048 + (hh - NH) * HD; wn = kw; scale = 1.0f; }
    float x0 = p[l], x1 = p[l + 64];
    float ss = x0 * x0 + x1 * x1;
#pragma unroll
    for (int off = 32; off; off >>= 1) ss += __shfl_xor(ss, off);
    float inv = rsqrtf(ss * (1.0f / 128.0f) + 1e-6f);
    x0 *= inv * wn[l];
    x1 *= inv * wn[l + 64];
    float invf = exp2f(-(float)l * (13.287712379549449f / 64.0f));
    float ang  = (float)s * invf;
    float c, sn;
    sincosf(ang, &sn, &c);
    p[l]      = (x0 * c - x1 * sn) * scale;
    p[l + 64] = (x1 * c + x0 * sn) * scale;
}

// ---- pack K tiles: per (kh,kt) a 16 KB image == desired LDS image ------
__global__ __launch_bounds__(256)
void pack_k(const float* __restrict__ qkv, __bf16* __restrict__ Kt)
{
    const int kt = blockIdx.x, kh = blockIdx.y, t = threadIdx.x;
    char* tile = (char*)Kt + ((size_t)(kh * 32 + kt)) * 16384;
    const float* src = qkv + 2048 + kh * HD;
#pragma unroll
    for (int i = 0; i < 4; ++i) {
        int cid = t * 4 + i;
        int key = cid >> 4, pc = cid & 15;
        int c = pc ^ (key & 15);
        const float* s = src + (size_t)(kt * 64 + key) * QS + c * 8;
        float4 a = *reinterpret_cast<const float4*>(s);
        float4 b = *reinterpret_cast<const float4*>(s + 4);
        *reinterpret_cast<bf8v*>(tile + cid * 16) =
            bf8v{ (__bf16)a.x, (__bf16)a.y, (__bf16)a.z, (__bf16)a.w,
                  (__bf16)b.x, (__bf16)b.y, (__bf16)b.z, (__bf16)b.w };
    }
}

// ---- pack V tiles transposed: image offset = d*128 + kcp*16 + j*2 ------
__global__ __launch_bounds__(256)
void pack_v(const float* __restrict__ qkv, __bf16* __restrict__ Vt)
{
    const int kt = blockIdx.x, kh = blockIdx.y, t = threadIdx.x;
    char* tile = (char*)Vt + ((size_t)(kh * 32 + kt)) * 16384;
    const float* src = qkv + 2560 + kh * HD;
#pragma unroll
    for (int i = 0; i < 4; ++i) {
        int cid = t * 4 + i;
        int d = cid >> 3, kcp = cid & 7;
        int kc = kcp ^ (d & 7);
        const float* s = src + (size_t)(kt * 64 + kc * 8) * QS + d;
        __bf16 tmp[8];
#pragma unroll
        for (int j = 0; j < 8; ++j) tmp[j] = (__bf16)s[(size_t)j * QS];
        *reinterpret_cast<bf8v*>(tile + cid * 16) = *reinterpret_cast<bf8v*>(tmp);
    }
}

// ---- split-K MFMA flash attention, STATIC-MAX softmax ------------------
// Scores |s|<=~11 (RMS-normed q,k, pre-scaled 1/sqrt(128)) -> exp(s) safe.
// No running max, no alpha rescale, no per-tile cross-lane reductions:
// row-sums accumulate per-lane, one butterfly in epilogue. LDS = 40960 B
// exactly -> 4 blocks/CU. qt reversed so 8-tile chains dispatch first.
__global__ __launch_bounds__(256)
void attn_split(const float* __restrict__ qkv,
                const __bf16* __restrict__ Kt, const __bf16* __restrict__ Vt,
                __bf16* __restrict__ Op, float* __restrict__ Lp)
{
    __shared__ char Ks[16384];
    __shared__ char Vs[16384];
    __shared__ char Ps[4][2048];   // per-wave P strip, xor-swizzled 16B chunks

    const int c = blockIdx.x, qt = 31 - blockIdx.y, h = blockIdx.z;
    if (c * 8 > qt) return;
    const int kend = min(qt, c * 8 + 7);
    const int tid = threadIdx.x, lane = tid & 63, w = tid >> 6;
    const int mm = lane & 15, quad = lane >> 4;
    const int kh = h >> 2;

    bf8v aq[4];
    const float* qbase = qkv + (size_t)(qt * 64 + w * 16 + mm) * QS + h * HD;
#pragma unroll
    for (int ks = 0; ks < 4; ++ks) {
        float4 f0 = *reinterpret_cast<const float4*>(qbase + ks * 32 + quad * 8);
        float4 f1 = *reinterpret_cast<const float4*>(qbase + ks * 32 + quad * 8 + 4);
        aq[ks] = bf8v{ (__bf16)f0.x, (__bf16)f0.y, (__bf16)f0.z, (__bf16)f0.w,
                       (__bf16)f1.x, (__bf16)f1.y, (__bf16)f1.z, (__bf16)f1.w };
    }

    float lp[4] = {};        // per-lane partial row-sums
    f4v oacc[8] = {};

    for (int kt = c * 8; kt <= kend; ++kt) {
        __syncthreads();
        const char* ktile = (const char*)Kt + ((size_t)(kh * 32 + kt)) * 16384;
        const char* vtile = (const char*)Vt + ((size_t)(kh * 32 + kt)) * 16384;
#pragma unroll
        for (int j = 0; j < 4; ++j) {
            int chunk = w * 4 + j;
            gld16(ktile + chunk * 1024 + lane * 16, Ks + chunk * 1024);
            gld16(vtile + chunk * 1024 + lane * 16, Vs + chunk * 1024);
        }
        __syncthreads();

        // S = Q K^T
        f4v s[4] = {};
#pragma unroll
        for (int ks = 0; ks < 4; ++ks)
#pragma unroll
            for (int c16 = 0; c16 < 4; ++c16) {
                bf8v b = *reinterpret_cast<const bf8v*>(
                    Ks + (c16 * 16 + mm) * 256 + (((ks * 4 + quad) ^ mm) << 4));
                s[c16] = __builtin_amdgcn_mfma_f32_16x16x32_bf16(aq[ks], b, s[c16], 0, 0, 0);
            }
        if (kt == qt) {
#pragma unroll
            for (int c16 = 0; c16 < 4; ++c16)
#pragma unroll
                for (int r = 0; r < 4; ++r)
                    if (c16 * 16 + mm > w * 16 + quad * 4 + r)
                        s[c16][r] = -__builtin_inff();
        }
        // static-max softmax: p = exp(s); accumulate per-lane row sums
        float pr[4][4];
#pragma unroll
        for (int c16 = 0; c16 < 4; ++c16)
#pragma unroll
            for (int r = 0; r < 4; ++r) {
                pr[c16][r] = __expf(s[c16][r]);   // exp(-inf)=0 handles mask
                lp[r] += pr[c16][r];
            }
        // P strip write: row roww=quad*4+r, key col c16*16+mm, pair-packed,
        // 16B chunk cc=c16*2+(mm>>3) stored at (cc ^ (roww&7))
#pragma unroll
        for (int c16 = 0; c16 < 4; ++c16)
#pragma unroll
            for (int r = 0; r < 4; ++r) {
                float mine  = pr[c16][r];
                float other = __shfl_xor(mine, 1);
                if ((mm & 1) == 0) {
                    int roww = quad * 4 + r;
                    int cc   = c16 * 2 + (mm >> 3);
                    *reinterpret_cast<bf2v*>(
                        &Ps[w][roww * 128 + ((cc ^ (roww & 7)) << 4) + (mm & 7) * 2]) =
                        bf2v{ (__bf16)mine, (__bf16)other };
                }
            }
        // A-frag read: row mm, chunk kb*4+quad at swizzle (..^ (mm&7))
        bf8v pa[2];
#pragma unroll
        for (int kb = 0; kb < 2; ++kb)
            pa[kb] = *reinterpret_cast<const bf8v*>(
                &Ps[w][mm * 128 + (((kb * 4 + quad) ^ (mm & 7)) << 4)]);
#pragma unroll
        for (int nb = 0; nb < 8; ++nb) {
            int d = nb * 16 + mm;
#pragma unroll
            for (int kb = 0; kb < 2; ++kb) {
                bf8v bv = *reinterpret_cast<const bf8v*>(
                    Vs + d * 128 + (((kb * 4 + quad) ^ (d & 7)) << 4));
                oacc[nb] = __builtin_amdgcn_mfma_f32_16x16x32_bf16(pa[kb], bv, oacc[nb], 0, 0, 0);
            }
        }
    }
    // epilogue: butterfly row-sum across the 16 mm lanes, write partials
#pragma unroll
    for (int off = 1; off < 16; off <<= 1)
#pragma unroll
        for (int r = 0; r < 4; ++r) lp[r] += __shfl_xor(lp[r], off);
#pragma unroll
    for (int r = 0; r < 4; ++r) {
        int row = qt * 64 + w * 16 + quad * 4 + r;
        size_t obase = ((size_t)(c * 16 + h) * SEQ + row) * HD;
#pragma unroll
        for (int nb = 0; nb < 8; ++nb)
            Op[obase + nb * 16 + mm] = (__bf16)oacc[nb][r];
        if (mm == 0)
            Lp[(size_t)(c * 16 + h) * SEQ + row] = lp[r];
    }
}

// ---- combine split-K partials -> ab (bf16 [row][h*128+d]) --------------
__global__ __launch_bounds__(64)
void combine(const __bf16* __restrict__ Op, const float* __restrict__ Lp,
             __bf16* __restrict__ ab)
{
    const int row = blockIdx.x, h = blockIdx.y, l = threadIdx.x;
    const int nch = (row >> 9) + 1;
    float L = 0.f, a0 = 0.f, a1 = 0.f;
    for (int c = 0; c < nch; ++c) {
        L += Lp[(size_t)(c * 16 + h) * SEQ + row];
        bf2v p = *reinterpret_cast<const bf2v*>(
            Op + ((size_t)(c * 16 + h) * SEQ + row) * HD + 2 * l);
        a0 += (float)p[0];
        a1 += (float)p[1];
    }
    float inv = 1.f / L;
    *reinterpret_cast<bf2v*>(ab + (size_t)row * (NH * HD) + h * HD + 2 * l) =
        bf2v{ (__bf16)(a0 * inv), (__bf16)(a1 * inv) };
}

extern "C" void kernel_launch(void* const* d_in, const int* in_sizes, int n_in,
                              void* d_out, int out_size, void* d_ws, size_t ws_size,
                              hipStream_t stream)
{
    const float* hs  = (const float*)d_in[0];
    const float* mu  = (const float*)d_in[1];
    const float* wq  = (const float*)d_in[2];
    const float* wk  = (const float*)d_in[3];
    const float* wv  = (const float*)d_in[4];
    const float* wo  = (const float*)d_in[5];
    const float* wmq = (const float*)d_in[6];
    const float* wmk = (const float*)d_in[7];
    const float* wmv = (const float*)d_in[8];
    const float* qw  = (const float*)d_in[9];
    const float* kw  = (const float*)d_in[10];
    float* out = (float*)d_out;

    char* ws = (char*)d_ws;
    __bf16* Wcat = (__bf16*)(ws + 0);          // [3072,4096] 25.2 MB
    __bf16* Acat = (__bf16*)(ws + 25165824);   // [2048,4096] 16.8 MB
    __bf16* Wo   = (__bf16*)(ws + 41943040);   // [2048,2048]  8.4 MB
    float*  qkv  = (float*) (ws + 50331648);   // [2048,3072] 25.2 MB
    __bf16* ab   = (__bf16*)(ws + 75497472);   // [2048,2048]  8.4 MB
    __bf16* Ktl  = (__bf16*)(ws + 0);          // 2 MB (aliases dead Wcat)
    __bf16* Vtl  = (__bf16*)(ws + 2097152);    // 2 MB
    __bf16* Opart= (__bf16*)(ws + 4194304);    // 32 MB
    float*  Lpart= (float*) (ws + 37748736);   // 0.5 MB

    cvt_cat2<<<dim3((2048 * 1024 + 255) / 256), 256, 0, stream>>>(Acat, hs, mu, 2048, 512);
    cvt_cat2<<<dim3((2048 * 1024 + 255) / 256), 256, 0, stream>>>(Wcat, wq, wmq, 2048, 512);
    cvt_cat2<<<dim3((512 * 1024 + 255) / 256), 256, 0, stream>>>(Wcat + (size_t)2048 * 4096, wk, wmk, 512, 512);
    cvt_cat2<<<dim3((512 * 1024 + 255) / 256), 256, 0, stream>>>(Wcat + (size_t)2560 * 4096, wv, wmv, 512, 512);
    cvt<<<dim3((1024 * 1024 + 255) / 256), 256, 0, stream>>>(Wo, wo, 1024 * 1024);

    gemm_nt<<<dim3(QS / 64, SEQ / 128), 256, 0, stream>>>(Acat, Wcat, qkv, SEQ, QS, 2 * HID_DIM);
    norm_rope<<<dim3(SEQ, NH + NKV), dim3(64), 0, stream>>>(qkv, qw, kw);
    pack_k<<<dim3(32, NKV), 256, 0, stream>>>(qkv, Ktl);
    pack_v<<<dim3(32, NKV), 256, 0, stream>>>(qkv, Vtl);
    attn_split<<<dim3(4, 32, NH), 256, 0, stream>>>(qkv, Ktl, Vtl, Opart, Lpart);
    combine<<<dim3(SEQ, NH), 64, 0, stream>>>(Opart, Lpart, ab);
    gemm_nt<<<dim3(HID_DIM / 64, SEQ / 128), 256, 0, stream>>>(ab, Wo, out, SEQ, HID_DIM, NH * HD);
}

// Round 8
// 367.438 us; speedup vs baseline: 6.7635x; 1.0410x over previous
//
#include <hip/hip_runtime.h>
#include <math.h>

#define SEQ 2048
#define HID_DIM 2048
#define NH 16
#define NKV 4
#define HD 128
#define QS 3072   // fused qkv row stride (bf16): [q 2048 | k 512 | v 512]

typedef float  f4v  __attribute__((ext_vector_type(4)));
typedef __bf16 bf8v __attribute__((ext_vector_type(8)));
typedef __bf16 bf4v __attribute__((ext_vector_type(4)));
typedef __bf16 bf2v __attribute__((ext_vector_type(2)));

typedef __attribute__((address_space(1))) const void* gvp;
typedef __attribute__((address_space(3))) void*       svp;

__device__ __forceinline__ void gld16(const void* g, void* lds_wave_base) {
    __builtin_amdgcn_global_load_lds((gvp)g, (svp)lds_wave_base, 16, 0, 0);
}

// ---- fp32 -> bf16 converts ---------------------------------------------
__global__ __launch_bounds__(256)
void cvt_cat2(__bf16* __restrict__ dst, const float* __restrict__ s0,
              const float* __restrict__ s1, int rows, int kq)
{
    int i = blockIdx.x * 256 + threadIdx.x;
    if (i >= rows * kq * 2) return;
    int row = i / (2 * kq), c = i - row * 2 * kq;
    const float* s = (c < kq) ? s0 + ((size_t)row * kq + c) * 4
                              : s1 + ((size_t)row * kq + (c - kq)) * 4;
    float4 v = *reinterpret_cast<const float4*>(s);
    *reinterpret_cast<bf4v*>(dst + ((size_t)row * 2 * kq + c) * 4) =
        bf4v{ (__bf16)v.x, (__bf16)v.y, (__bf16)v.z, (__bf16)v.w };
}

__global__ __launch_bounds__(256)
void cvt(__bf16* __restrict__ dst, const float* __restrict__ src, int n4)
{
    int i = blockIdx.x * 256 + threadIdx.x;
    if (i >= n4) return;
    float4 v = *reinterpret_cast<const float4*>(src + (size_t)i * 4);
    *reinterpret_cast<bf4v*>(dst + (size_t)i * 4) =
        bf4v{ (__bf16)v.x, (__bf16)v.y, (__bf16)v.z, (__bf16)v.w };
}

// ---- split-K NT GEMM, 128x128 tile (m97 wave-tile 64x64), bf16 partials.
__global__ __launch_bounds__(256)
void gemm_nt_sp(const __bf16* __restrict__ A, const __bf16* __restrict__ B,
                __bf16* __restrict__ P, int M, int N, int K, int KS)
{
    __shared__ __bf16 As[128 * 32];
    __shared__ __bf16 Bs[128 * 32];
    const int tid = threadIdx.x, lane = tid & 63, w = tid >> 6;
    const int wm = w >> 1, wn = w & 1;
    const int mm = lane & 15, quad = lane >> 4;
    const int m0 = blockIdx.y * 128, n0 = blockIdx.x * 128;
    const int kz0 = blockIdx.z * KS;
    const int r0 = lane >> 2, c0 = (lane & 3) * 8;

    f4v acc[4][4] = {};

    for (int k0 = kz0; k0 < kz0 + KS; k0 += 32) {
#pragma unroll
        for (int j = 0; j < 2; ++j) {
            int chunk = w * 2 + j;
            int row   = chunk * 16 + r0;
            gld16(&A[(size_t)(m0 + row) * K + k0 + c0], (char*)As + chunk * 1024);
            gld16(&B[(size_t)(n0 + row) * K + k0 + c0], (char*)Bs + chunk * 1024);
        }
        __syncthreads();
        bf8v af[4], bfv[4];
#pragma unroll
        for (int t = 0; t < 4; ++t) {
            af[t]  = *reinterpret_cast<const bf8v*>(&As[(wm * 64 + t * 16 + mm) * 32 + quad * 8]);
            bfv[t] = *reinterpret_cast<const bf8v*>(&Bs[(wn * 64 + t * 16 + mm) * 32 + quad * 8]);
        }
#pragma unroll
        for (int mt = 0; mt < 4; ++mt)
#pragma unroll
            for (int nt = 0; nt < 4; ++nt)
                acc[mt][nt] = __builtin_amdgcn_mfma_f32_16x16x32_bf16(af[mt], bfv[nt], acc[mt][nt], 0, 0, 0);
        __syncthreads();
    }
    __bf16* Pz = P + (size_t)blockIdx.z * M * N;
#pragma unroll
    for (int mt = 0; mt < 4; ++mt)
#pragma unroll
        for (int nt = 0; nt < 4; ++nt)
#pragma unroll
            for (int r = 0; r < 4; ++r)
                Pz[(size_t)(m0 + wm * 64 + mt * 16 + quad * 4 + r) * N
                   + n0 + wn * 64 + nt * 16 + mm] = (__bf16)acc[mt][nt][r];
}

// ---- sum 4 bf16 partials -> fp32 out -----------------------------------
__global__ __launch_bounds__(256)
void add4(const __bf16* __restrict__ P, float* __restrict__ out, int n4)
{
    int i = blockIdx.x * 256 + threadIdx.x;
    if (i >= n4) return;
    float4 s = {0.f, 0.f, 0.f, 0.f};
#pragma unroll
    for (int z = 0; z < 4; ++z) {
        bf4v v = *reinterpret_cast<const bf4v*>(P + (size_t)z * n4 * 4 + (size_t)i * 4);
        s.x += (float)v[0]; s.y += (float)v[1]; s.z += (float)v[2]; s.w += (float)v[3];
    }
    *reinterpret_cast<float4*>(out + (size_t)i * 4) = s;
}

// ---- norm_rope: sum 2 GEMM partials (q,k heads), RMSNorm + RoPE --------
__global__ __launch_bounds__(64)
void norm_rope(__bf16* __restrict__ qkv /* p0, in place */,
               const __bf16* __restrict__ p1,
               const float* __restrict__ qw, const float* __restrict__ kw)
{
    const int s = blockIdx.x, hh = blockIdx.y, l = threadIdx.x;
    const float* wn; float scale; int off;
    if (hh < NH) { off = hh * HD;               wn = qw; scale = 0.08838834764831845f; }
    else         { off = 2048 + (hh - NH) * HD; wn = kw; scale = 1.0f; }
    __bf16* p = qkv + (size_t)s * QS + off;
    const __bf16* q1 = p1 + (size_t)s * QS + off;
    float x0 = (float)p[l]      + (float)q1[l];
    float x1 = (float)p[l + 64] + (float)q1[l + 64];
    float ss = x0 * x0 + x1 * x1;
#pragma unroll
    for (int o = 32; o; o >>= 1) ss += __shfl_xor(ss, o);
    float inv = rsqrtf(ss * (1.0f / 128.0f) + 1e-6f);
    x0 *= inv * wn[l];
    x1 *= inv * wn[l + 64];
    float invf = exp2f(-(float)l * (13.287712379549449f / 64.0f));
    float ang  = (float)s * invf;
    float c, sn;
    sincosf(ang, &sn, &c);
    p[l]      = (__bf16)((x0 * c - x1 * sn) * scale);
    p[l + 64] = (__bf16)((x1 * c + x0 * sn) * scale);
}

// ---- pack K tiles: per (kh,kt) a 16 KB image == desired LDS image ------
__global__ __launch_bounds__(256)
void pack_k(const __bf16* __restrict__ qkv, __bf16* __restrict__ Kt)
{
    const int kt = blockIdx.x, kh = blockIdx.y, t = threadIdx.x;
    char* tile = (char*)Kt + ((size_t)(kh * 32 + kt)) * 16384;
    const __bf16* src = qkv + 2048 + kh * HD;
#pragma unroll
    for (int i = 0; i < 4; ++i) {
        int cid = t * 4 + i;
        int key = cid >> 4, pc = cid & 15;
        int c = pc ^ (key & 15);
        bf8v v = *reinterpret_cast<const bf8v*>(src + (size_t)(kt * 64 + key) * QS + c * 8);
        *reinterpret_cast<bf8v*>(tile + cid * 16) = v;
    }
}

// ---- pack V tiles transposed; V = p0 + p1 (v skips norm_rope!) ---------
__global__ __launch_bounds__(256)
void pack_v(const __bf16* __restrict__ qkv0, const __bf16* __restrict__ qkv1,
            __bf16* __restrict__ Vt)
{
    const int kt = blockIdx.x, kh = blockIdx.y, t = threadIdx.x;
    char* tile = (char*)Vt + ((size_t)(kh * 32 + kt)) * 16384;
    const __bf16* s0 = qkv0 + 2560 + kh * HD;
    const __bf16* s1 = qkv1 + 2560 + kh * HD;
#pragma unroll
    for (int i = 0; i < 4; ++i) {
        int cid = t * 4 + i;
        int d = cid >> 3, kcp = cid & 7;
        int kc = kcp ^ (d & 7);
        size_t base = (size_t)(kt * 64 + kc * 8) * QS + d;
        __bf16 tmp[8];
#pragma unroll
        for (int j = 0; j < 8; ++j)
            tmp[j] = (__bf16)((float)s0[base + (size_t)j * QS] +
                              (float)s1[base + (size_t)j * QS]);
        *reinterpret_cast<bf8v*>(tile + cid * 16) = *reinterpret_cast<bf8v*>(tmp);
    }
}

// ---- split-K MFMA flash attention, static-max softmax ------------------
__global__ __launch_bounds__(256)
void attn_split(const __bf16* __restrict__ qkv,
                const __bf16* __restrict__ Kt, const __bf16* __restrict__ Vt,
                __bf16* __restrict__ Op, float* __restrict__ Lp)
{
    __shared__ char Ks[16384];
    __shared__ char Vs[16384];
    __shared__ char Ps[4][2048];

    const int c = blockIdx.x, qt = 31 - blockIdx.y, h = blockIdx.z;
    if (c * 8 > qt) return;
    const int kend = min(qt, c * 8 + 7);
    const int tid = threadIdx.x, lane = tid & 63, w = tid >> 6;
    const int mm = lane & 15, quad = lane >> 4;
    const int kh = h >> 2;

    bf8v aq[4];
    const __bf16* qbase = qkv + (size_t)(qt * 64 + w * 16 + mm) * QS + h * HD;
#pragma unroll
    for (int ks = 0; ks < 4; ++ks)
        aq[ks] = *reinterpret_cast<const bf8v*>(qbase + ks * 32 + quad * 8);

    float lp[4] = {};
    f4v oacc[8] = {};

    for (int kt = c * 8; kt <= kend; ++kt) {
        __syncthreads();
        const char* ktile = (const char*)Kt + ((size_t)(kh * 32 + kt)) * 16384;
        const char* vtile = (const char*)Vt + ((size_t)(kh * 32 + kt)) * 16384;
#pragma unroll
        for (int j = 0; j < 4; ++j) {
            int chunk = w * 4 + j;
            gld16(ktile + chunk * 1024 + lane * 16, Ks + chunk * 1024);
            gld16(vtile + chunk * 1024 + lane * 16, Vs + chunk * 1024);
        }
        __syncthreads();

        f4v s[4] = {};
#pragma unroll
        for (int ks = 0; ks < 4; ++ks)
#pragma unroll
            for (int c16 = 0; c16 < 4; ++c16) {
                bf8v b = *reinterpret_cast<const bf8v*>(
                    Ks + (c16 * 16 + mm) * 256 + (((ks * 4 + quad) ^ mm) << 4));
                s[c16] = __builtin_amdgcn_mfma_f32_16x16x32_bf16(aq[ks], b, s[c16], 0, 0, 0);
            }
        if (kt == qt) {
#pragma unroll
            for (int c16 = 0; c16 < 4; ++c16)
#pragma unroll
                for (int r = 0; r < 4; ++r)
                    if (c16 * 16 + mm > w * 16 + quad * 4 + r)
                        s[c16][r] = -__builtin_inff();
        }
        float pr[4][4];
#pragma unroll
        for (int c16 = 0; c16 < 4; ++c16)
#pragma unroll
            for (int r = 0; r < 4; ++r) {
                pr[c16][r] = __expf(s[c16][r]);
                lp[r] += pr[c16][r];
            }
#pragma unroll
        for (int c16 = 0; c16 < 4; ++c16)
#pragma unroll
            for (int r = 0; r < 4; ++r) {
                float mine  = pr[c16][r];
                float other = __shfl_xor(mine, 1);
                if ((mm & 1) == 0) {
                    int roww = quad * 4 + r;
                    int cc   = c16 * 2 + (mm >> 3);
                    *reinterpret_cast<bf2v*>(
                        &Ps[w][roww * 128 + ((cc ^ (roww & 7)) << 4) + (mm & 7) * 2]) =
                        bf2v{ (__bf16)mine, (__bf16)other };
                }
            }
        bf8v pa[2];
#pragma unroll
        for (int kb = 0; kb < 2; ++kb)
            pa[kb] = *reinterpret_cast<const bf8v*>(
                &Ps[w][mm * 128 + (((kb * 4 + quad) ^ (mm & 7)) << 4)]);
#pragma unroll
        for (int nb = 0; nb < 8; ++nb) {
            int d = nb * 16 + mm;
#pragma unroll
            for (int kb = 0; kb < 2; ++kb) {
                bf8v bv = *reinterpret_cast<const bf8v*>(
                    Vs + d * 128 + (((kb * 4 + quad) ^ (d & 7)) << 4));
                oacc[nb] = __builtin_amdgcn_mfma_f32_16x16x32_bf16(pa[kb], bv, oacc[nb], 0, 0, 0);
            }
        }
    }
#pragma unroll
    for (int off = 1; off < 16; off <<= 1)
#pragma unroll
        for (int r = 0; r < 4; ++r) lp[r] += __shfl_xor(lp[r], off);
#pragma unroll
    for (int r = 0; r < 4; ++r) {
        int row = qt * 64 + w * 16 + quad * 4 + r;
        size_t obase = ((size_t)(c * 16 + h) * SEQ + row) * HD;
#pragma unroll
        for (int nb = 0; nb < 8; ++nb)
            Op[obase + nb * 16 + mm] = (__bf16)oacc[nb][r];
        if (mm == 0)
            Lp[(size_t)(c * 16 + h) * SEQ + row] = lp[r];
    }
}

// ---- combine split-K partials -> ab (bf16 [row][h*128+d]) --------------
__global__ __launch_bounds__(64)
void combine(const __bf16* __restrict__ Op, const float* __restrict__ Lp,
             __bf16* __restrict__ ab)
{
    const int row = blockIdx.x, h = blockIdx.y, l = threadIdx.x;
    const int nch = (row >> 9) + 1;
    float L = 0.f, a0 = 0.f, a1 = 0.f;
    for (int c = 0; c < nch; ++c) {
        L += Lp[(size_t)(c * 16 + h) * SEQ + row];
        bf2v p = *reinterpret_cast<const bf2v*>(
            Op + ((size_t)(c * 16 + h) * SEQ + row) * HD + 2 * l);
        a0 += (float)p[0];
        a1 += (float)p[1];
    }
    float inv = 1.f / L;
    *reinterpret_cast<bf2v*>(ab + (size_t)row * (NH * HD) + h * HD + 2 * l) =
        bf2v{ (__bf16)(a0 * inv), (__bf16)(a1 * inv) };
}

extern "C" void kernel_launch(void* const* d_in, const int* in_sizes, int n_in,
                              void* d_out, int out_size, void* d_ws, size_t ws_size,
                              hipStream_t stream)
{
    const float* hs  = (const float*)d_in[0];
    const float* mu  = (const float*)d_in[1];
    const float* wq  = (const float*)d_in[2];
    const float* wk  = (const float*)d_in[3];
    const float* wv  = (const float*)d_in[4];
    const float* wo  = (const float*)d_in[5];
    const float* wmq = (const float*)d_in[6];
    const float* wmk = (const float*)d_in[7];
    const float* wmv = (const float*)d_in[8];
    const float* qw  = (const float*)d_in[9];
    const float* kw  = (const float*)d_in[10];
    float* out = (float*)d_out;

    char* ws = (char*)d_ws;
    // phase 1 (projection):
    __bf16* Wcat = (__bf16*)(ws + 0);          // [3072,4096] 25.2 MB
    __bf16* Acat = (__bf16*)(ws + 25165824);   // [2048,4096] 16.8 MB
    __bf16* Wo   = (__bf16*)(ws + 41943040);   // [2048,2048]  8.4 MB
    __bf16* qkvp = (__bf16*)(ws + 50331648);   // 2x[2048,3072] bf16 partials
    __bf16* ab   = (__bf16*)(ws + 75497472);   // [2048,2048] bf16, peak 83.9 MB
    // phase 2 aliases (Wcat/Acat dead after QKV GEMM):
    __bf16* Ktl  = (__bf16*)(ws + 0);          // 2 MB
    __bf16* Vtl  = (__bf16*)(ws + 2097152);    // 2 MB
    __bf16* Opart= (__bf16*)(ws + 4194304);    // 32 MB (ends 37.7 MB)
    float*  Lpart= (float*) (ws + 37748736);   // 0.5 MB
    // phase 3 alias (attn scratch dead after combine):
    __bf16* outp = (__bf16*)(ws + 0);          // 4x[2048,2048] bf16 = 33.6 MB

    cvt_cat2<<<dim3((2048 * 1024 + 255) / 256), 256, 0, stream>>>(Acat, hs, mu, 2048, 512);
    cvt_cat2<<<dim3((2048 * 1024 + 255) / 256), 256, 0, stream>>>(Wcat, wq, wmq, 2048, 512);
    cvt_cat2<<<dim3((512 * 1024 + 255) / 256), 256, 0, stream>>>(Wcat + (size_t)2048 * 4096, wk, wmk, 512, 512);
    cvt_cat2<<<dim3((512 * 1024 + 255) / 256), 256, 0, stream>>>(Wcat + (size_t)2560 * 4096, wv, wmv, 512, 512);
    cvt<<<dim3((1024 * 1024 + 255) / 256), 256, 0, stream>>>(Wo, wo, 1024 * 1024);

    // QKV projection, split-K=2: grid 24x16x2 = 768 blocks = 3/CU
    gemm_nt_sp<<<dim3(QS / 128, SEQ / 128, 2), 256, 0, stream>>>(Acat, Wcat, qkvp, SEQ, QS, 2 * HID_DIM, HID_DIM);
    norm_rope<<<dim3(SEQ, NH + NKV), dim3(64), 0, stream>>>(qkvp, qkvp + (size_t)SEQ * QS, qw, kw);
    pack_k<<<dim3(32, NKV), 256, 0, stream>>>(qkvp, Ktl);
    pack_v<<<dim3(32, NKV), 256, 0, stream>>>(qkvp, qkvp + (size_t)SEQ * QS, Vtl);
    attn_split<<<dim3(4, 32, NH), 256, 0, stream>>>(qkvp, Ktl, Vtl, Opart, Lpart);
    combine<<<dim3(SEQ, NH), 64, 0, stream>>>(Opart, Lpart, ab);
    // output projection, split-K=4: grid 16x16x4 = 1024 blocks = 4/CU
    gemm_nt_sp<<<dim3(HID_DIM / 128, SEQ / 128, 4), 256, 0, stream>>>(ab, Wo, outp, SEQ, HID_DIM, NH * HD, 512);
    add4<<<dim3((1024 * 1024 + 255) / 256), 256, 0, stream>>>(outp, out, 1024 * 1024);
}